// Round 14
// baseline (516.883 us; speedup 1.0000x reference)
//
#include <hip/hip_runtime.h>

#define INVBN 0.9999950000374997f       // 1/sqrt(1 + 1e-5)
#define ATT_SCALE 0.17677669529663687f  // 32^-0.5

typedef short bf16x8 __attribute__((ext_vector_type(8)));
typedef float f32x4  __attribute__((ext_vector_type(4)));
typedef unsigned short us8v __attribute__((ext_vector_type(8)));

#define AS1C(p) ((const __attribute__((address_space(1))) void*)(p))
#define AS3(p)  ((__attribute__((address_space(3))) void*)(p))

#define VMCNT_BARRIER(Nstr) do {                                   \
    asm volatile("s_waitcnt vmcnt(" Nstr ")" ::: "memory");        \
    __builtin_amdgcn_s_barrier(); } while (0)

__device__ __forceinline__ float bf2f(unsigned short u) {
    return __uint_as_float(((unsigned)u) << 16);
}
__device__ __forceinline__ unsigned short f2bf(float f) {
    unsigned u = __float_as_uint(f);
    u += 0x7FFFu + ((u >> 16) & 1u);        // RNE
    return (unsigned short)(u >> 16);
}

// ---------------------------------------------------------------------------
// Repack: Wt3[tap][m][k] bf16 (BN-folded conv3x3 + lc1 into center tap),
// Wq, Wpw bf16, bsum[m] = b1+b2, PLUS Swin bias in MFMA C-layout (merged).
// ---------------------------------------------------------------------------
__global__ __launch_bounds__(256)
void repack_kernel(const float* __restrict__ W2, const float* __restrict__ W1,
                   const float* __restrict__ Wq, const float* __restrict__ Wp,
                   const float* __restrict__ g1, const float* __restrict__ g2,
                   const float* __restrict__ b1, const float* __restrict__ b2,
                   const float* __restrict__ RT,
                   unsigned short* __restrict__ Wt, unsigned short* __restrict__ WqO,
                   unsigned short* __restrict__ WpO, float* __restrict__ bsum,
                   float* __restrict__ biasM)
{
    int i = blockIdx.x * 256 + threadIdx.x;
    if (i < 512) bsum[i] = b1[i] + b2[i];
    if (i < 786432) WqO[i] = f2bf(Wq[i]);
    if (i < 262144) WpO[i] = f2bf(Wp[i]);
    if (i < 16384) {                       // Swin bias in MFMA C-layout
        int h = i >> 10, rem = i & 1023;
        int frag = rem >> 6, lane = rem & 63;
        int fi = frag >> 2, fj = frag & 3;
        int q  = 16 * fj + (lane & 15);
        int kb = 16 * fi + ((lane >> 4) << 2);
        int yi = q >> 3, xi = q & 7;
        float4 o;
        float* op = (float*)&o;
#pragma unroll
        for (int r = 0; r < 4; ++r) {
            int j = kb + r;
            int ridx = (yi - (j >> 3) + 7) * 15 + (xi - (j & 7) + 7);
            op[r] = RT[ridx * 16 + h];
        }
        *(float4*)&biasM[(size_t)i * 4] = o;
    }
    if (i >= 2359296) return;
    int tap = i / 262144;
    int rem = i - tap * 262144;          // m*512 + k
    int m   = rem >> 9;
    float v = g2[m] * INVBN * W2[(size_t)rem * 9 + tap];
    if (tap == 4) v = fmaf(g1[m] * INVBN, W1[rem], v);
    Wt[i] = f2bf(v);
}

// ---------------------------------------------------------------------------
// x (B,512,64,64) f32 NCHW  ->  X_tp (B, 66*66, 512) bf16, zero borders.
// ---------------------------------------------------------------------------
__global__ __launch_bounds__(256)
void pad_transpose_kernel(const float* __restrict__ X, unsigned short* __restrict__ XT)
{
    int ph = blockIdx.x;      // 0..65
    int b  = blockIdx.y;
    int t  = threadIdx.x;
    unsigned short* rowbase = XT + ((size_t)b * 4356 + (size_t)ph * 66) * 512;
    uint4 z = make_uint4(0, 0, 0, 0);
    if (ph == 0 || ph == 65) {
        uint4* p4 = (uint4*)rowbase;                 // 66*512 elems = 4224 uint4
        for (int i = t; i < 4224; i += 256) p4[i] = z;
        return;
    }
    if (t < 64)       ((uint4*)rowbase)[t] = z;                  // pw = 0
    else if (t < 128) ((uint4*)(rowbase + 65 * 512))[t - 64] = z; // pw = 65

    int h = ph - 1;
    __shared__ float tile[64][65];
    const float* xb = X + (size_t)b * 512 * 4096 + h * 64;
    for (int cc = 0; cc < 8; ++cc) {
        int c0 = cc * 64;
        __syncthreads();
#pragma unroll
        for (int i = 0; i < 4; ++i) {
            int cl = i * 16 + (t >> 4);
            int w0 = (t & 15) * 4;
            *(float4*)&tile[cl][w0] =
                *(const float4*)&xb[(size_t)(c0 + cl) * 4096 + w0];
        }
        __syncthreads();
#pragma unroll
        for (int it = 0; it < 2; ++it) {
            int wl = it * 32 + (t >> 3);     // w = 0..63  -> pw = wl+1
            int cs = (t & 7) * 8;
            us8v v;
#pragma unroll
            for (int e = 0; e < 8; ++e) v[e] = f2bf(tile[cs + e][wl]);
            *(us8v*)&rowbase[(size_t)(1 + wl) * 512 + c0 + cs] = v;
        }
    }
}

// ---------------------------------------------------------------------------
// 256x256 MFMA GEMM (round-9 structure — best measured).  8 waves, BK=32,
// 4 LDS buffers (128 KiB), vmcnt(8) ledger, chunk XOR-swizzle.
// ---------------------------------------------------------------------------
template<int NTAPS, bool PAD, typename OT>
__global__ __launch_bounds__(512, 2)
void mfma_gemm256(const unsigned short* __restrict__ A,
                  const unsigned short* __restrict__ Bw,
                  const float* __restrict__ bias,
                  OT* __restrict__ Out, int M)
{
    __shared__ __align__(16) unsigned short ldsbuf[65536];   // 128 KiB

    const int t    = threadIdx.x;
    const int wid  = t >> 6, lane = t & 63;
    const int wr   = wid >> 2, wc = wid & 3;
    const int lrow = lane & 15, lk = lane >> 4;
    const int n0 = blockIdx.x * 256;
    const int m0 = blockIdx.y * 256;
    const int b  = blockIdx.z;
    const unsigned short* Ab = A + (size_t)b * (PAD ? 4356 * 512 : 4096 * 512);
    OT* Ob = Out + (size_t)b * ((size_t)M * 4096);

    const unsigned short* src[4];
    {
        int rsub = lane >> 2, ch = lane & 3;
        int chs  = ch ^ ((rsub >> 1) & 3);
#pragma unroll
        for (int i = 0; i < 4; ++i) {
            if (wid < 4) {
                int p = n0 + (wid * 4 + i) * 16 + rsub;
                if (PAD) {
                    int h = p >> 6, w = p & 63;
                    src[i] = Ab + (size_t)((h + 1) * 66 + (w + 1)) * 512 + chs * 8;
                } else {
                    src[i] = Ab + (size_t)p * 512 + chs * 8;
                }
            } else {
                int m = m0 + ((wid - 4) * 4 + i) * 16 + rsub;
                src[i] = Bw + (size_t)m * 512 + chs * 8;
            }
        }
    }

    f32x4 acc[8][4] = {};
    const int ck0 = (lk ^ ((lrow >> 1) & 3)) * 8;

    auto aScal = [&](int tt) -> int {
        if (NTAPS == 1) return tt * 32;
        int tap = tt >> 4;
        return (tap / 3 - 1) * (66 * 512) + (tap % 3 - 1) * 512 + (tt & 15) * 32;
    };
    auto bScal = [&](int tt) -> int {
        if (NTAPS == 1) return tt * 32;
        return (tt >> 4) * (M * 512) + (tt & 15) * 32;
    };
    auto STAGE = [&](int bufk, int aoff, int boff) {
        int off = (wid < 4) ? aoff : boff;
#pragma unroll
        for (int i = 0; i < 4; ++i)
            __builtin_amdgcn_global_load_lds(
                AS1C(src[i] + off),
                AS3(&ldsbuf[bufk * 16384 + (wid * 4 + i) * 512]), 16, 0, 0);
    };
    auto COMPUTE = [&](int bufk) {
        const unsigned short* Ak = &ldsbuf[bufk * 16384];
        const unsigned short* Bk = &ldsbuf[bufk * 16384 + 8192];
        bf16x8 af[8], bfr[4];
#pragma unroll
        for (int f = 0; f < 8; ++f)
            af[f] = *(const bf16x8*)&Ak[(wr * 128 + f * 16 + lrow) * 32 + ck0];
#pragma unroll
        for (int g = 0; g < 4; ++g)
            bfr[g] = *(const bf16x8*)&Bk[(wc * 64 + g * 16 + lrow) * 32 + ck0];
        __builtin_amdgcn_s_setprio(1);
#pragma unroll
        for (int f = 0; f < 8; ++f)
#pragma unroll
            for (int g = 0; g < 4; ++g)
                acc[f][g] = __builtin_amdgcn_mfma_f32_16x16x32_bf16(
                    af[f], bfr[g], acc[f][g], 0, 0, 0);
        __builtin_amdgcn_s_setprio(0);
    };

    constexpr int NT = NTAPS * 16;

    STAGE(0, aScal(0), bScal(0));
    STAGE(1, aScal(1), bScal(1));
    STAGE(2, aScal(2), bScal(2));
    VMCNT_BARRIER("8");

#pragma unroll 1
    for (int tb = 0; tb < NT - 4; tb += 4) {
        STAGE(3, aScal(tb + 3), bScal(tb + 3)); COMPUTE(0); VMCNT_BARRIER("8");
        STAGE(0, aScal(tb + 4), bScal(tb + 4)); COMPUTE(1); VMCNT_BARRIER("8");
        STAGE(1, aScal(tb + 5), bScal(tb + 5)); COMPUTE(2); VMCNT_BARRIER("8");
        STAGE(2, aScal(tb + 6), bScal(tb + 6)); COMPUTE(3); VMCNT_BARRIER("8");
    }
    STAGE(3, aScal(NT - 1), bScal(NT - 1)); COMPUTE(0); VMCNT_BARRIER("8");
    COMPUTE(1); VMCNT_BARRIER("4");
    COMPUTE(2); VMCNT_BARRIER("0");
    COMPUTE(3);

#pragma unroll
    for (int g = 0; g < 4; ++g) {
        int m = m0 + wc * 64 + g * 16 + lrow;
        float bv = bias ? bias[m] : 0.f;
        size_t mrow = (size_t)m * 4096;
#pragma unroll
        for (int f = 0; f < 8; ++f) {
            int nb = n0 + wr * 128 + f * 16 + lk * 4;
            f32x4 a4 = acc[f][g];
            if constexpr (sizeof(OT) == 2) {
                ushort4 o;
                o.x = f2bf(a4[0] + bv);
                o.y = f2bf(a4[1] + bv);
                o.z = f2bf(a4[2] + bv);
                o.w = f2bf(a4[3] + bv);
                *(ushort4*)&Ob[mrow + nb] = o;
            } else {
                *(float4*)&Ob[mrow + nb] =
                    make_float4(a4[0] + bv, a4[1] + bv, a4[2] + bv, a4[3] + bv);
            }
        }
    }
}

// ---------------------------------------------------------------------------
// FUSED qkv + window attention.  Block = (headgroup, window, batch); 4 waves,
// 1 head each.  Window tokens (64x512 bf16) staged once into LDS (chunk
// XOR-swizzle sigma(tk)=tk&7, both sides).  Each wave computes Q,K,V for its
// head via MFMA (A = tokens from LDS, B = weight rows from global / L2),
// stores bf16 into per-wave LDS (Q,K token-major stride 36; V ch-major
// stride 72; P overlays Q+K), then runs the proven attention body.
// D-layout convention (refcheck-verified): B-row <-> lane&15, A-row <-> lk*4+r.
// ---------------------------------------------------------------------------
__global__ __launch_bounds__(256)
void fused_qkv_attn_kernel(const unsigned short* __restrict__ XT,
                           const unsigned short* __restrict__ W,
                           const float* __restrict__ biasM,
                           unsigned short* __restrict__ OutB)
{
    __shared__ __align__(16) unsigned short xts[32768];   // [64 tok][512 ch] swizzled
    __shared__ short pws[4][6912];                        // per wave: QK/P + V

    int t = threadIdx.x;
    int wid = t >> 6, lane = t & 63;
    int wing = blockIdx.y, b = blockIdx.z;
    int head = blockIdx.x * 4 + wid;
    int hhi = wing >> 3, wwi = wing & 7;
    int sp0 = hhi * 512 + wwi * 8;
    int ch0 = head * 32;
    const unsigned short* xtb = XT + (size_t)b * (4356 * 512);

    // ---- stage window tokens: wave covers one token per round (64 chunks
    //      = 64 lanes); dest = uniform + lane*16B; source chunk pre-swizzled.
#pragma unroll
    for (int rd = 0; rd < 16; ++rd) {
        int tk  = rd * 4 + wid;
        int rr  = tk >> 3, cdx = tk & 7;
        int grow = (hhi * 8 + rr + 1) * 66 + (wwi * 8 + cdx + 1);
        int cs  = lane ^ (tk & 7);
        __builtin_amdgcn_global_load_lds(
            AS1C(xtb + (size_t)grow * 512 + cs * 8),
            AS3(&xts[tk * 512 + lane * 8]), 16, 0, 0);
    }
    asm volatile("s_waitcnt vmcnt(0)" ::: "memory");
    __builtin_amdgcn_s_barrier();

    int lrow = lane & 15, lk = lane >> 4;
    short* Qtm = pws[wid];             // [64][36]
    short* Ktm = Qtm + 2304;           // [64][36]
    short* Vtm = Qtm + 4608;           // [32][72]
    short* Pq  = Qtm;                  // [64][72] overlays Q+K after S

    // ---- compute Q, K, V (M = xt @ Wm^T), store bf16 to LDS ----
#pragma unroll 1
    for (int mtx = 0; mtx < 3; ++mtx) {
        const unsigned short* wbase = W + (size_t)(mtx * 512 + ch0) * 512;
        f32x4 aq[4][2] = {};
#pragma unroll
        for (int ks = 0; ks < 16; ++ks) {
            bf16x8 b0 = *(const bf16x8*)&wbase[(size_t)lrow * 512 + ks * 32 + lk * 8];
            bf16x8 b1 = *(const bf16x8*)&wbase[(size_t)(16 + lrow) * 512 + ks * 32 + lk * 8];
#pragma unroll
            for (int tf = 0; tf < 4; ++tf) {
                int row = tf * 16 + lrow;
                int cc  = (ks * 4 + lk) ^ (row & 7);
                bf16x8 af = *(const bf16x8*)&xts[row * 512 + cc * 8];
                aq[tf][0] = __builtin_amdgcn_mfma_f32_16x16x32_bf16(af, b0, aq[tf][0], 0, 0, 0);
                aq[tf][1] = __builtin_amdgcn_mfma_f32_16x16x32_bf16(af, b1, aq[tf][1], 0, 0, 0);
            }
        }
        // D value = Mat[token = 16*tf + lk*4 + r][ch = 16*cf + lrow]
        if (mtx < 2) {
            short* dst = (mtx == 0) ? Qtm : Ktm;
#pragma unroll
            for (int tf = 0; tf < 4; ++tf)
#pragma unroll
                for (int cf = 0; cf < 2; ++cf)
#pragma unroll
                    for (int r = 0; r < 4; ++r)
                        dst[(16 * tf + lk * 4 + r) * 36 + 16 * cf + lrow] =
                            (short)f2bf(aq[tf][cf][r]);
        } else {
#pragma unroll
            for (int tf = 0; tf < 4; ++tf)
#pragma unroll
                for (int cf = 0; cf < 2; ++cf)
#pragma unroll
                    for (int r = 0; r < 4; ++r)
                        Vtm[(16 * cf + lrow) * 72 + 16 * tf + lk * 4 + r] =
                            (short)f2bf(aq[tf][cf][r]);
        }
    }

    // ---- attention body (identical to proven kernel) ----
    bf16x8 kf[4], qf[4];
#pragma unroll
    for (int f = 0; f < 4; ++f) {
        kf[f] = *(const bf16x8*)&Ktm[(lrow + 16 * f) * 36 + lk * 8];
        qf[f] = *(const bf16x8*)&Qtm[(lrow + 16 * f) * 36 + lk * 8];
    }
    f32x4 s[4][4] = {};
#pragma unroll
    for (int fi = 0; fi < 4; ++fi)
#pragma unroll
        for (int fj = 0; fj < 4; ++fj)
            s[fi][fj] = __builtin_amdgcn_mfma_f32_16x16x32_bf16(
                kf[fi], qf[fj], s[fi][fj], 0, 0, 0);

    const float* bM = biasM + (size_t)head * 4096;
    float rs[4];
#pragma unroll
    for (int fj = 0; fj < 4; ++fj) {
        float v[4][4];
#pragma unroll
        for (int fi = 0; fi < 4; ++fi) {
            float4 bv = *(const float4*)&bM[((fi * 4 + fj) * 64 + lane) * 4];
            const float* bvp = (const float*)&bv;
#pragma unroll
            for (int r = 0; r < 4; ++r)
                v[fi][r] = fmaf(s[fi][fj][r], ATT_SCALE, bvp[r]);
        }
        float m = -1e30f;
#pragma unroll
        for (int fi = 0; fi < 4; ++fi)
#pragma unroll
            for (int r = 0; r < 4; ++r) m = fmaxf(m, v[fi][r]);
        m = fmaxf(m, __shfl_xor(m, 16));
        m = fmaxf(m, __shfl_xor(m, 32));
        float ev[4][4];
        float sum = 0.f;
#pragma unroll
        for (int fi = 0; fi < 4; ++fi)
#pragma unroll
            for (int r = 0; r < 4; ++r) {
                ev[fi][r] = __expf(v[fi][r] - m);
                sum += ev[fi][r];
            }
        sum += __shfl_xor(sum, 16);
        sum += __shfl_xor(sum, 32);
        rs[fj] = 1.f / sum;
#pragma unroll
        for (int fi = 0; fi < 4; ++fi) {
            unsigned p0 = (unsigned)f2bf(ev[fi][0]) | ((unsigned)f2bf(ev[fi][1]) << 16);
            unsigned p1 = (unsigned)f2bf(ev[fi][2]) | ((unsigned)f2bf(ev[fi][3]) << 16);
            *(uint2*)&Pq[(lrow + 16 * fj) * 72 + 16 * fi + lk * 4] = make_uint2(p0, p1);
        }
    }

    f32x4 o[2][4] = {};
#pragma unroll
    for (int ks = 0; ks < 2; ++ks) {
        bf16x8 vf[2], pf[4];
#pragma unroll
        for (int fid = 0; fid < 2; ++fid)
            vf[fid] = *(const bf16x8*)&Vtm[(16 * fid + lrow) * 72 + (lk + 4 * ks) * 8];
#pragma unroll
        for (int fjq = 0; fjq < 4; ++fjq)
            pf[fjq] = *(const bf16x8*)&Pq[(lrow + 16 * fjq) * 72 + ks * 32 + lk * 8];
#pragma unroll
        for (int fid = 0; fid < 2; ++fid)
#pragma unroll
            for (int fjq = 0; fjq < 4; ++fjq)
                o[fid][fjq] = __builtin_amdgcn_mfma_f32_16x16x32_bf16(
                    vf[fid], pf[fjq], o[fid][fjq], 0, 0, 0);
    }

    // bounce O through the (dead) Pq region, then coalesced 16B stores.
#pragma unroll
    for (int fjq = 0; fjq < 4; ++fjq) {
        int q = lrow + 16 * fjq;
        float rr = rs[fjq];
#pragma unroll
        for (int fid = 0; fid < 2; ++fid) {
            int dch = 16 * fid + lk * 4;
#pragma unroll
            for (int r = 0; r < 4; ++r)
                Pq[(dch + r) * 72 + q] = (short)f2bf(o[fid][fjq][r] * rr);
        }
    }
    unsigned short* Out = OutB + (size_t)b * 512 * 4096;
#pragma unroll
    for (int j = 0; j < 4; ++j) {
        int dch  = lane & 31;
        int tokc = (lane >> 5) + 2 * j;
        us8v vv = *(const us8v*)&Pq[dch * 72 + tokc * 8];
        *(us8v*)&Out[(size_t)(ch0 + dch) * 4096 + sp0 + tokc * 64] = vv;
    }
}

// ---------------------------------------------------------------------------
// Fused pool(+local) + depthwise 8x8 + BN3 (8-wide pixel groups).
// ---------------------------------------------------------------------------
__global__ __launch_bounds__(256)
void pooldw_kernel(const unsigned short* __restrict__ A, const unsigned short* __restrict__ L,
                   const float* __restrict__ Wd,
                   const float* __restrict__ g3, const float* __restrict__ b3,
                   unsigned short* __restrict__ U)
{
    int bc = blockIdx.x;               // b*512 + c
    int c  = bc & 511;
    __shared__ float pad[72][72];      // 20.25 KB
    int t = threadIdx.x;
    float* pf = &pad[0][0];
#pragma unroll
    for (int i = 0; i < 21; ++i) {
        int e = i * 256 + t;
        if (e < 5184) pf[e] = 0.f;
    }
    __syncthreads();

    const unsigned short* ap = A + (size_t)bc * 4096;
#pragma unroll
    for (int i = 0; i < 4; ++i) {
        int idx = i * 256 + t;             // 1024 ushort4
        int y = idx >> 4, x4 = (idx & 15) * 4;
        ushort4 a4 = ((const ushort4*)ap)[idx];
        *(float4*)&pad[3 + y][4 + x4] =
            make_float4(bf2f(a4.x), bf2f(a4.y), bf2f(a4.z), bf2f(a4.w));
    }
    if (t < 64)       pad[67][4 + t] = bf2f(ap[62 * 64 + t]);
    else if (t < 128) { int y = t - 64; pad[3 + y][68] = bf2f(ap[y * 64 + 62]); }
    else if (t == 128) pad[67][68] = bf2f(ap[62 * 64 + 62]);
    __syncthreads();

    const unsigned short* lp = L + (size_t)bc * 4096;
    int u  = t & 7, rr = t >> 3;       // 8 w-groups x 32 row-phases
    int w0 = u * 8;
    float res[2][8];
#pragma unroll
    for (int g = 0; g < 2; ++g) {
        int h = g * 32 + rr;
        float4 sxlo = make_float4(0.f, 0.f, 0.f, 0.f);
        float4 sxhi = make_float4(0.f, 0.f, 0.f, 0.f);
#pragma unroll
        for (int i = 0; i < 8; ++i) {
            float4 a = *(const float4*)&pad[h + i][4 + w0];
            float4 bq = *(const float4*)&pad[h + i][8 + w0];
            sxlo.x += a.x; sxlo.y += a.y; sxlo.z += a.z; sxlo.w += a.w;
            sxhi.x += bq.x; sxhi.y += bq.y; sxhi.z += bq.z; sxhi.w += bq.w;
        }
        float sx[8] = {sxlo.x, sxlo.y, sxlo.z, sxlo.w, sxhi.x, sxhi.y, sxhi.z, sxhi.w};
        float win[16];
        *(float4*)&win[0]  = *(const float4*)&pad[3 + h][w0];
        *(float4*)&win[4]  = *(const float4*)&pad[3 + h][w0 + 4];
        *(float4*)&win[8]  = *(const float4*)&pad[3 + h][w0 + 8];
        *(float4*)&win[12] = *(const float4*)&pad[3 + h][w0 + 12];
        us8v l8 = *(const us8v*)&lp[h * 64 + w0];
#pragma unroll
        for (int p = 0; p < 8; ++p) {
            float sy = 0.f;
#pragma unroll
            for (int i = 1; i <= 8; ++i) sy += win[p + i];
            res[g][p] = fmaf(0.125f, sx[p] + sy, bf2f((unsigned short)l8[p]));
        }
    }
    __syncthreads();

#pragma unroll
    for (int g = 0; g < 2; ++g) {
        int h = g * 32 + rr;
        *(float4*)&pad[3 + h][4 + w0] = make_float4(res[g][0], res[g][1], res[g][2], res[g][3]);
        *(float4*)&pad[3 + h][8 + w0] = make_float4(res[g][4], res[g][5], res[g][6], res[g][7]);
    }
    __syncthreads();
    if (t < 64)       pad[67][4 + t] = pad[65][4 + t];
    else if (t < 128) { int y = t - 64; pad[3 + y][68] = pad[3 + y][66]; }
    else if (t == 128) pad[67][68] = pad[65][66];
    __syncthreads();

    const float* wdp = Wd + c * 64;
    float gc  = g3[c] * INVBN;
    float bcv = b3[c];
#pragma unroll
    for (int g = 0; g < 2; ++g) {
        int h = g * 32 + rr;
        float acc2[8];
#pragma unroll
        for (int p = 0; p < 8; ++p) acc2[p] = 0.f;
#pragma unroll
        for (int i = 0; i < 8; ++i) {
            float win[16];
            *(float4*)&win[0]  = *(const float4*)&pad[h + i][w0];
            *(float4*)&win[4]  = *(const float4*)&pad[h + i][w0 + 4];
            *(float4*)&win[8]  = *(const float4*)&pad[h + i][w0 + 8];
            *(float4*)&win[12] = *(const float4*)&pad[h + i][w0 + 12];
#pragma unroll
            for (int j = 0; j < 8; ++j) {
                float wv = wdp[i * 8 + j];
#pragma unroll
                for (int p = 0; p < 8; ++p)
                    acc2[p] = fmaf(wv, win[p + 1 + j], acc2[p]);
            }
        }
        us8v o8;
#pragma unroll
        for (int p = 0; p < 8; ++p) o8[p] = (short)f2bf(gc * acc2[p] + bcv);
        *(us8v*)&U[(size_t)bc * 4096 + h * 64 + w0] = o8;
    }
}

// ---------------------------------------------------------------------------
// U (B,512,4096) bf16 -> Ut (B,4096,512) bf16.  64p x 64c LDS tiles.
// ---------------------------------------------------------------------------
__global__ __launch_bounds__(256)
void transpose_cp_kernel(const unsigned short* __restrict__ U, unsigned short* __restrict__ Ut)
{
    int pt = blockIdx.x;               // p-tile 0..63
    int b  = blockIdx.y;
    const unsigned short* Ub = U + (size_t)b * 512 * 4096;
    unsigned short* Utb = Ut + (size_t)b * 4096 * 512;
    __shared__ unsigned short tile[64][72];
    int t = threadIdx.x;
    int p0 = pt * 64;

    for (int cc = 0; cc < 8; ++cc) {
        int c0 = cc * 64;
        __syncthreads();
        {
            int cl = t >> 2, px = (t & 3) * 16;
            const unsigned short* src = &Ub[(size_t)(c0 + cl) * 4096 + p0 + px];
            *(us8v*)&tile[cl][px]     = *(const us8v*)src;
            *(us8v*)&tile[cl][px + 8] = *(const us8v*)(src + 8);
        }
        __syncthreads();
        {
            int pl = t >> 2, cx = (t & 3) * 16;
            us8v o0, o1;
#pragma unroll
            for (int e = 0; e < 8; ++e) {
                o0[e] = tile[cx + e][pl];
                o1[e] = tile[cx + 8 + e][pl];
            }
            unsigned short* dst = &Utb[(size_t)(p0 + pl) * 512 + c0 + cx];
            *(us8v*)dst       = o0;
            *(us8v*)(dst + 8) = o1;
        }
    }
}

// ---------------------------------------------------------------------------
extern "C" void kernel_launch(void* const* d_in, const int* in_sizes, int n_in,
                              void* d_out, int out_size, void* d_ws, size_t ws_size,
                              hipStream_t stream)
{
    (void)in_sizes; (void)n_in; (void)out_size; (void)ws_size;
    const float* x     = (const float*)d_in[0];
    const float* w_lc1 = (const float*)d_in[1];
    const float* g1    = (const float*)d_in[2];
    const float* b1    = (const float*)d_in[3];
    const float* w_lc2 = (const float*)d_in[4];
    const float* g2    = (const float*)d_in[5];
    const float* b2    = (const float*)d_in[6];
    const float* w_qkv = (const float*)d_in[7];
    const float* rt    = (const float*)d_in[8];
    const float* w_dw  = (const float*)d_in[9];
    const float* g3    = (const float*)d_in[10];
    const float* b3    = (const float*)d_in[11];
    const float* w_pw  = (const float*)d_in[12];
    float* out = (float*)d_out;

    // workspace (bf16 short offsets), total 55,329,792 sh = 110.7 MB:
    //   local : [0 .. 16,777,216)
    //   xt    : [16,777,216 .. 34,619,392)   (stays live through fused attn)
    //   wt3   : [34,619,392 .. 36,978,688)
    //   wq    : [36,978,688 .. 37,765,120)
    //   wpw   : [37,765,120 .. 38,027,264)
    //   bsum  : [38,027,264 .. 38,028,288)  (f32)
    //   biasM : [38,028,288 .. 38,552,576)  (f32)
    //   attnO : [38,552,576 .. 55,329,792)  (bf16; U overwrites in place)
    unsigned short* S        = (unsigned short*)d_ws;
    unsigned short* local_us = S;
    unsigned short* xt_us    = S + 16777216;
    unsigned short* wt3_us   = S + 34619392;
    unsigned short* wq_us    = S + 36978688;
    unsigned short* wpw_us   = S + 37765120;
    float*          bsum     = (float*)(S + 38027264);
    float*          biasM    = (float*)(S + 38028288);
    unsigned short* attnO    = S + 38552576;
    unsigned short* u_us     = attnO;                   // U in-place over attnO
    unsigned short* ut_us    = local_us;                // Ut after local dead

    repack_kernel<<<dim3(9216), 256, 0, stream>>>(w_lc2, w_lc1, w_qkv, w_pw,
                                                  g1, g2, b1, b2, rt,
                                                  wt3_us, wq_us, wpw_us, bsum, biasM);
    pad_transpose_kernel<<<dim3(66, 8), 256, 0, stream>>>(x, xt_us);
    mfma_gemm256<9, true, unsigned short><<<dim3(16, 2, 8), 512, 0, stream>>>(
        xt_us, wt3_us, bsum, local_us, 512);
    fused_qkv_attn_kernel<<<dim3(4, 64, 8), 256, 0, stream>>>(
        xt_us, wq_us, biasM, attnO);
    pooldw_kernel<<<dim3(4096), 256, 0, stream>>>(attnO, local_us, w_dw, g3, b3, u_us);
    transpose_cp_kernel<<<dim3(64, 8), 256, 0, stream>>>(u_us, ut_us);
    mfma_gemm256<1, false, float><<<dim3(16, 2, 8), 512, 0, stream>>>(
        ut_us, wpw_us, nullptr, out, 512);
}

// Round 15
// 466.309 us; speedup vs baseline: 1.1085x; 1.1085x over previous
//
#include <hip/hip_runtime.h>

#define INVBN 0.9999950000374997f       // 1/sqrt(1 + 1e-5)
#define ATT_SCALE 0.17677669529663687f  // 32^-0.5

typedef short bf16x8 __attribute__((ext_vector_type(8)));
typedef float f32x4  __attribute__((ext_vector_type(4)));
typedef unsigned short us8v __attribute__((ext_vector_type(8)));

#define AS1C(p) ((const __attribute__((address_space(1))) void*)(p))
#define AS3(p)  ((__attribute__((address_space(3))) void*)(p))

#define VMCNT_BARRIER(Nstr) do {                                   \
    asm volatile("s_waitcnt vmcnt(" Nstr ")" ::: "memory");        \
    __builtin_amdgcn_s_barrier(); } while (0)

__device__ __forceinline__ float bf2f(unsigned short u) {
    return __uint_as_float(((unsigned)u) << 16);
}
__device__ __forceinline__ unsigned short f2bf(float f) {
    unsigned u = __float_as_uint(f);
    u += 0x7FFFu + ((u >> 16) & 1u);        // RNE
    return (unsigned short)(u >> 16);
}

// ---------------------------------------------------------------------------
// Repack: Wt3[tap][m][k] bf16 (BN-folded conv3x3 + lc1 into center tap),
// Wq, Wpw bf16, bsum[m] = b1+b2, PLUS Swin bias in MFMA C-layout (merged).
// ---------------------------------------------------------------------------
__global__ __launch_bounds__(256)
void repack_kernel(const float* __restrict__ W2, const float* __restrict__ W1,
                   const float* __restrict__ Wq, const float* __restrict__ Wp,
                   const float* __restrict__ g1, const float* __restrict__ g2,
                   const float* __restrict__ b1, const float* __restrict__ b2,
                   const float* __restrict__ RT,
                   unsigned short* __restrict__ Wt, unsigned short* __restrict__ WqO,
                   unsigned short* __restrict__ WpO, float* __restrict__ bsum,
                   float* __restrict__ biasM)
{
    int i = blockIdx.x * 256 + threadIdx.x;
    if (i < 512) bsum[i] = b1[i] + b2[i];
    if (i < 786432) WqO[i] = f2bf(Wq[i]);
    if (i < 262144) WpO[i] = f2bf(Wp[i]);
    if (i < 16384) {                       // Swin bias in MFMA C-layout
        int h = i >> 10, rem = i & 1023;
        int frag = rem >> 6, lane = rem & 63;
        int fi = frag >> 2, fj = frag & 3;
        int q  = 16 * fj + (lane & 15);
        int kb = 16 * fi + ((lane >> 4) << 2);
        int yi = q >> 3, xi = q & 7;
        float4 o;
        float* op = (float*)&o;
#pragma unroll
        for (int r = 0; r < 4; ++r) {
            int j = kb + r;
            int ridx = (yi - (j >> 3) + 7) * 15 + (xi - (j & 7) + 7);
            op[r] = RT[ridx * 16 + h];
        }
        *(float4*)&biasM[(size_t)i * 4] = o;
    }
    if (i >= 2359296) return;
    int tap = i / 262144;
    int rem = i - tap * 262144;          // m*512 + k
    int m   = rem >> 9;
    float v = g2[m] * INVBN * W2[(size_t)rem * 9 + tap];
    if (tap == 4) v = fmaf(g1[m] * INVBN, W1[rem], v);
    Wt[i] = f2bf(v);
}

// ---------------------------------------------------------------------------
// x (B,512,64,64) f32 NCHW  ->  X_tp (B, 66*66, 512) bf16, zero borders.
// ---------------------------------------------------------------------------
__global__ __launch_bounds__(256)
void pad_transpose_kernel(const float* __restrict__ X, unsigned short* __restrict__ XT)
{
    int ph = blockIdx.x;      // 0..65
    int b  = blockIdx.y;
    int t  = threadIdx.x;
    unsigned short* rowbase = XT + ((size_t)b * 4356 + (size_t)ph * 66) * 512;
    uint4 z = make_uint4(0, 0, 0, 0);
    if (ph == 0 || ph == 65) {
        uint4* p4 = (uint4*)rowbase;                 // 66*512 elems = 4224 uint4
        for (int i = t; i < 4224; i += 256) p4[i] = z;
        return;
    }
    if (t < 64)       ((uint4*)rowbase)[t] = z;                  // pw = 0
    else if (t < 128) ((uint4*)(rowbase + 65 * 512))[t - 64] = z; // pw = 65

    int h = ph - 1;
    __shared__ float tile[64][65];
    const float* xb = X + (size_t)b * 512 * 4096 + h * 64;
    for (int cc = 0; cc < 8; ++cc) {
        int c0 = cc * 64;
        __syncthreads();
#pragma unroll
        for (int i = 0; i < 4; ++i) {
            int cl = i * 16 + (t >> 4);
            int w0 = (t & 15) * 4;
            *(float4*)&tile[cl][w0] =
                *(const float4*)&xb[(size_t)(c0 + cl) * 4096 + w0];
        }
        __syncthreads();
#pragma unroll
        for (int it = 0; it < 2; ++it) {
            int wl = it * 32 + (t >> 3);     // w = 0..63  -> pw = wl+1
            int cs = (t & 7) * 8;
            us8v v;
#pragma unroll
            for (int e = 0; e < 8; ++e) v[e] = f2bf(tile[cs + e][wl]);
            *(us8v*)&rowbase[(size_t)(1 + wl) * 512 + c0 + cs] = v;
        }
    }
}

// ---------------------------------------------------------------------------
// 256x256 MFMA GEMM (round-9 structure — best measured: conv 149.8 us,
// MfmaUtil 45.4, 0 bank conflicts).  8 waves, BK=32, 4 LDS buffers (128 KiB),
// vmcnt(8) counted ledger, chunk XOR-swizzle sigma(r) = ((r&15)>>1)&3
// (pre-swizzled global source + swizzled ds_read; linear gload_lds dest).
// A: PAD ? (B,66*66,512) padded-transposed : (B,4096,512) linear.
// Out: bf16 or f32 per OT.
// ---------------------------------------------------------------------------
template<int NTAPS, bool PAD, typename OT>
__global__ __launch_bounds__(512, 2)
void mfma_gemm256(const unsigned short* __restrict__ A,
                  const unsigned short* __restrict__ Bw,
                  const float* __restrict__ bias,
                  OT* __restrict__ Out, int M)
{
    __shared__ __align__(16) unsigned short ldsbuf[65536];   // 128 KiB

    const int t    = threadIdx.x;
    const int wid  = t >> 6, lane = t & 63;
    const int wr   = wid >> 2, wc = wid & 3;          // wave n-half / m-quarter
    const int lrow = lane & 15, lk = lane >> 4;
    const int n0 = blockIdx.x * 256;
    const int m0 = blockIdx.y * 256;
    const int b  = blockIdx.z;
    const unsigned short* Ab = A + (size_t)b * (PAD ? 4356 * 512 : 4096 * 512);
    OT* Ob = Out + (size_t)b * ((size_t)M * 4096);

    // --- staging source pointers: waves 0-3 stage A (256 spatial rows),
    //     waves 4-7 stage B (256 weight rows).  Source chunk pre-swizzled:
    //     LDS slot (rsub, ch) receives global chunk ch ^ sigma(rsub). ---
    const unsigned short* src[4];
    {
        int rsub = lane >> 2, ch = lane & 3;
        int chs  = ch ^ ((rsub >> 1) & 3);            // inverse swizzle on source
#pragma unroll
        for (int i = 0; i < 4; ++i) {
            if (wid < 4) {
                int p = n0 + (wid * 4 + i) * 16 + rsub;
                if (PAD) {
                    int h = p >> 6, w = p & 63;
                    src[i] = Ab + (size_t)((h + 1) * 66 + (w + 1)) * 512 + chs * 8;
                } else {
                    src[i] = Ab + (size_t)p * 512 + chs * 8;
                }
            } else {
                int m = m0 + ((wid - 4) * 4 + i) * 16 + rsub;
                src[i] = Bw + (size_t)m * 512 + chs * 8;
            }
        }
    }

    f32x4 acc[8][4] = {};

    // fragment chunk indices (swizzled reads)
    const int ck0 = (lk ^ ((lrow >> 1) & 3)) * 8;

    auto aScal = [&](int tt) -> int {
        if (NTAPS == 1) return tt * 32;
        int tap = tt >> 4;
        return (tap / 3 - 1) * (66 * 512) + (tap % 3 - 1) * 512 + (tt & 15) * 32;
    };
    auto bScal = [&](int tt) -> int {
        if (NTAPS == 1) return tt * 32;
        return (tt >> 4) * (M * 512) + (tt & 15) * 32;
    };
    auto STAGE = [&](int bufk, int aoff, int boff) {
        int off = (wid < 4) ? aoff : boff;
#pragma unroll
        for (int i = 0; i < 4; ++i)
            __builtin_amdgcn_global_load_lds(
                AS1C(src[i] + off),
                AS3(&ldsbuf[bufk * 16384 + (wid * 4 + i) * 512]), 16, 0, 0);
    };
    auto COMPUTE = [&](int bufk) {
        const unsigned short* Ak = &ldsbuf[bufk * 16384];
        const unsigned short* Bk = &ldsbuf[bufk * 16384 + 8192];
        bf16x8 af[8], bfr[4];
#pragma unroll
        for (int f = 0; f < 8; ++f)
            af[f] = *(const bf16x8*)&Ak[(wr * 128 + f * 16 + lrow) * 32 + ck0];
#pragma unroll
        for (int g = 0; g < 4; ++g)
            bfr[g] = *(const bf16x8*)&Bk[(wc * 64 + g * 16 + lrow) * 32 + ck0];
        __builtin_amdgcn_s_setprio(1);
#pragma unroll
        for (int f = 0; f < 8; ++f)
#pragma unroll
            for (int g = 0; g < 4; ++g)
                acc[f][g] = __builtin_amdgcn_mfma_f32_16x16x32_bf16(
                    af[f], bfr[g], acc[f][g], 0, 0, 0);
        __builtin_amdgcn_s_setprio(0);
    };

    constexpr int NT = NTAPS * 16;               // K-tiles of 32 (>= 16, mult of 4)

    // prologue: stage tiles 0,1,2; wait tile0 (outstanding: tiles 1,2 = 8)
    STAGE(0, aScal(0), bScal(0));
    STAGE(1, aScal(1), bScal(1));
    STAGE(2, aScal(2), bScal(2));
    VMCNT_BARRIER("8");

    // steady state: compute tile t (buf t%4), stage tile t+3 (buf (t+3)%4,
    // freed by the barrier ending tile t-1); end wait = tiles t+2,t+3 in
    // flight (8 loads) -> tile t+1 ready.
#pragma unroll 1
    for (int tb = 0; tb < NT - 4; tb += 4) {
        STAGE(3, aScal(tb + 3), bScal(tb + 3)); COMPUTE(0); VMCNT_BARRIER("8");
        STAGE(0, aScal(tb + 4), bScal(tb + 4)); COMPUTE(1); VMCNT_BARRIER("8");
        STAGE(1, aScal(tb + 5), bScal(tb + 5)); COMPUTE(2); VMCNT_BARRIER("8");
        STAGE(2, aScal(tb + 6), bScal(tb + 6)); COMPUTE(3); VMCNT_BARRIER("8");
    }
    // tail: tiles NT-4..NT-1 (NT ≡ 0 mod 4), drain 8 -> 4 -> 0
    STAGE(3, aScal(NT - 1), bScal(NT - 1)); COMPUTE(0); VMCNT_BARRIER("8");
    COMPUTE(1); VMCNT_BARRIER("4");
    COMPUTE(2); VMCNT_BARRIER("0");
    COMPUTE(3);

    // --- epilogue: bias + store (D: col m uses lrow, rows n use lk*4+r) ---
#pragma unroll
    for (int g = 0; g < 4; ++g) {
        int m = m0 + wc * 64 + g * 16 + lrow;
        float bv = bias ? bias[m] : 0.f;
        size_t mrow = (size_t)m * 4096;
#pragma unroll
        for (int f = 0; f < 8; ++f) {
            int nb = n0 + wr * 128 + f * 16 + lk * 4;
            f32x4 a4 = acc[f][g];
            if constexpr (sizeof(OT) == 2) {
                ushort4 o;
                o.x = f2bf(a4[0] + bv);
                o.y = f2bf(a4[1] + bv);
                o.z = f2bf(a4[2] + bv);
                o.w = f2bf(a4[3] + bv);
                *(ushort4*)&Ob[mrow + nb] = o;
            } else {
                *(float4*)&Ob[mrow + nb] =
                    make_float4(a4[0] + bv, a4[1] + bv, a4[2] + bv, a4[3] + bv);
            }
        }
    }
}

// ---------------------------------------------------------------------------
// MFMA window attention: 1 wave per (window, head), 4 waves/block.
// Output bf16 via per-wave LDS bounce -> coalesced 16B stores.
// ---------------------------------------------------------------------------
__global__ __launch_bounds__(256)
void attn_mfma_kernel(const unsigned short* __restrict__ QKV,
                      const float* __restrict__ biasM,
                      unsigned short* __restrict__ OutB)
{
    __shared__ short smem[4 * 9216];
    int t = threadIdx.x;
    int wv = t >> 6, lane = t & 63;
    int wing = blockIdx.x >> 2;
    int head = (blockIdx.x & 3) * 4 + wv;
    int b    = blockIdx.y;
    int hhi = wing >> 3, wwi = wing & 7;
    int sp0 = hhi * 512 + wwi * 8;
    int ch0 = head * 32;
    const unsigned short* Qg = QKV + (size_t)b * 1536 * 4096;

    short* Qtm = smem + wv * 9216;     // [64][36] token-major Q
    short* Ktm = Qtm + 2304;           // [64][36] token-major K
    short* Pq  = Qtm + 4608;           // [64][72] P (q-major); reused as O-bounce

    {
        int d  = lane & 31;
        int rb = lane >> 5;
#pragma unroll
        for (int i = 0; i < 4; ++i) {
            int r = rb + 2 * i;        // window row 0..7
            us8v q8 = *(const us8v*)&Qg[(size_t)(ch0 + d) * 4096 + sp0 + r * 64];
            us8v k8 = *(const us8v*)&Qg[(size_t)(512 + ch0 + d) * 4096 + sp0 + r * 64];
#pragma unroll
            for (int e = 0; e < 8; ++e) {
                Qtm[(r * 8 + e) * 36 + d] = (short)q8[e];
                Ktm[(r * 8 + e) * 36 + d] = (short)k8[e];
            }
        }
    }

    int lrow = lane & 15, lk = lane >> 4;

    bf16x8 kf[4], qf[4];
#pragma unroll
    for (int f = 0; f < 4; ++f) {
        kf[f] = *(const bf16x8*)&Ktm[(lrow + 16 * f) * 36 + lk * 8];
        qf[f] = *(const bf16x8*)&Qtm[(lrow + 16 * f) * 36 + lk * 8];
    }
    f32x4 s[4][4] = {};
#pragma unroll
    for (int fi = 0; fi < 4; ++fi)
#pragma unroll
        for (int fj = 0; fj < 4; ++fj)
            s[fi][fj] = __builtin_amdgcn_mfma_f32_16x16x32_bf16(
                kf[fi], qf[fj], s[fi][fj], 0, 0, 0);

    const float* bM = biasM + (size_t)head * 4096;
    float rs[4];
#pragma unroll
    for (int fj = 0; fj < 4; ++fj) {
        float v[4][4];
#pragma unroll
        for (int fi = 0; fi < 4; ++fi) {
            float4 bv = *(const float4*)&bM[((fi * 4 + fj) * 64 + lane) * 4];
            const float* bvp = (const float*)&bv;
#pragma unroll
            for (int r = 0; r < 4; ++r)
                v[fi][r] = fmaf(s[fi][fj][r], ATT_SCALE, bvp[r]);
        }
        float m = -1e30f;
#pragma unroll
        for (int fi = 0; fi < 4; ++fi)
#pragma unroll
            for (int r = 0; r < 4; ++r) m = fmaxf(m, v[fi][r]);
        m = fmaxf(m, __shfl_xor(m, 16));
        m = fmaxf(m, __shfl_xor(m, 32));
        float ev[4][4];
        float sum = 0.f;
#pragma unroll
        for (int fi = 0; fi < 4; ++fi)
#pragma unroll
            for (int r = 0; r < 4; ++r) {
                ev[fi][r] = __expf(v[fi][r] - m);
                sum += ev[fi][r];
            }
        sum += __shfl_xor(sum, 16);
        sum += __shfl_xor(sum, 32);
        rs[fj] = 1.f / sum;
#pragma unroll
        for (int fi = 0; fi < 4; ++fi) {
            unsigned p0 = (unsigned)f2bf(ev[fi][0]) | ((unsigned)f2bf(ev[fi][1]) << 16);
            unsigned p1 = (unsigned)f2bf(ev[fi][2]) | ((unsigned)f2bf(ev[fi][3]) << 16);
            *(uint2*)&Pq[(lrow + 16 * fj) * 72 + 16 * fi + lk * 4] = make_uint2(p0, p1);
        }
    }

    f32x4 o[2][4] = {};
#pragma unroll
    for (int ks = 0; ks < 2; ++ks) {
        bf16x8 vf[2], pf[4];
#pragma unroll
        for (int fid = 0; fid < 2; ++fid)
            vf[fid] = *(const bf16x8*)&Qg[(size_t)(1024 + ch0 + 16 * fid + lrow) * 4096
                                          + sp0 + (lk + 4 * ks) * 64];
#pragma unroll
        for (int fjq = 0; fjq < 4; ++fjq)
            pf[fjq] = *(const bf16x8*)&Pq[(lrow + 16 * fjq) * 72 + ks * 32 + lk * 8];
#pragma unroll
        for (int fid = 0; fid < 2; ++fid)
#pragma unroll
            for (int fjq = 0; fjq < 4; ++fjq)
                o[fid][fjq] = __builtin_amdgcn_mfma_f32_16x16x32_bf16(
                    vf[fid], pf[fjq], o[fid][fjq], 0, 0, 0);
    }

    // bounce O through the (now-dead) Pq region, then coalesced 16B stores.
#pragma unroll
    for (int fjq = 0; fjq < 4; ++fjq) {
        int q = lrow + 16 * fjq;
        float rr = rs[fjq];
#pragma unroll
        for (int fid = 0; fid < 2; ++fid) {
            int dch = 16 * fid + lk * 4;
#pragma unroll
            for (int r = 0; r < 4; ++r)
                Pq[(dch + r) * 72 + q] = (short)f2bf(o[fid][fjq][r] * rr);
        }
    }
    unsigned short* Out = OutB + (size_t)b * 512 * 4096;
#pragma unroll
    for (int j = 0; j < 4; ++j) {
        int dch  = lane & 31;
        int tokc = (lane >> 5) + 2 * j;    // window row 0..7
        us8v vv = *(const us8v*)&Pq[dch * 72 + tokc * 8];
        *(us8v*)&Out[(size_t)(ch0 + dch) * 4096 + sp0 + tokc * 64] = vv;
    }
}

// ---------------------------------------------------------------------------
// Fused pool(+local) + depthwise 8x8 + BN3: single 72x72 LDS tile,
// 8-wide pixel groups, b128 LDS traffic, dw weights via scalar loads.
// A bf16; U may alias A (per-plane read-before-write).
// ---------------------------------------------------------------------------
__global__ __launch_bounds__(256)
void pooldw_kernel(const unsigned short* __restrict__ A, const unsigned short* __restrict__ L,
                   const float* __restrict__ Wd,
                   const float* __restrict__ g3, const float* __restrict__ b3,
                   unsigned short* __restrict__ U)
{
    int bc = blockIdx.x;               // b*512 + c
    int c  = bc & 511;
    __shared__ float pad[72][72];      // 20.25 KB
    int t = threadIdx.x;
    float* pf = &pad[0][0];
#pragma unroll
    for (int i = 0; i < 21; ++i) {
        int e = i * 256 + t;
        if (e < 5184) pf[e] = 0.f;
    }
    __syncthreads();

    const unsigned short* ap = A + (size_t)bc * 4096;
#pragma unroll
    for (int i = 0; i < 4; ++i) {
        int idx = i * 256 + t;             // 1024 ushort4
        int y = idx >> 4, x4 = (idx & 15) * 4;
        ushort4 a4 = ((const ushort4*)ap)[idx];
        *(float4*)&pad[3 + y][4 + x4] =
            make_float4(bf2f(a4.x), bf2f(a4.y), bf2f(a4.z), bf2f(a4.w));
    }
    if (t < 64)       pad[67][4 + t] = bf2f(ap[62 * 64 + t]);
    else if (t < 128) { int y = t - 64; pad[3 + y][68] = bf2f(ap[y * 64 + 62]); }
    else if (t == 128) pad[67][68] = bf2f(ap[62 * 64 + 62]);
    __syncthreads();

    const unsigned short* lp = L + (size_t)bc * 4096;
    int u  = t & 7, rr = t >> 3;       // 8 w-groups x 32 row-phases
    int w0 = u * 8;
    float res[2][8];
#pragma unroll
    for (int g = 0; g < 2; ++g) {
        int h = g * 32 + rr;
        float4 sxlo = make_float4(0.f, 0.f, 0.f, 0.f);
        float4 sxhi = make_float4(0.f, 0.f, 0.f, 0.f);
#pragma unroll
        for (int i = 0; i < 8; ++i) {
            float4 a = *(const float4*)&pad[h + i][4 + w0];
            float4 bq = *(const float4*)&pad[h + i][8 + w0];
            sxlo.x += a.x; sxlo.y += a.y; sxlo.z += a.z; sxlo.w += a.w;
            sxhi.x += bq.x; sxhi.y += bq.y; sxhi.z += bq.z; sxhi.w += bq.w;
        }
        float sx[8] = {sxlo.x, sxlo.y, sxlo.z, sxlo.w, sxhi.x, sxhi.y, sxhi.z, sxhi.w};
        float win[16];
        *(float4*)&win[0]  = *(const float4*)&pad[3 + h][w0];
        *(float4*)&win[4]  = *(const float4*)&pad[3 + h][w0 + 4];
        *(float4*)&win[8]  = *(const float4*)&pad[3 + h][w0 + 8];
        *(float4*)&win[12] = *(const float4*)&pad[3 + h][w0 + 12];
        us8v l8 = *(const us8v*)&lp[h * 64 + w0];
#pragma unroll
        for (int p = 0; p < 8; ++p) {
            float sy = 0.f;
#pragma unroll
            for (int i = 1; i <= 8; ++i) sy += win[p + i];
            res[g][p] = fmaf(0.125f, sx[p] + sy, bf2f((unsigned short)l8[p]));
        }
    }
    __syncthreads();

#pragma unroll
    for (int g = 0; g < 2; ++g) {
        int h = g * 32 + rr;
        *(float4*)&pad[3 + h][4 + w0] = make_float4(res[g][0], res[g][1], res[g][2], res[g][3]);
        *(float4*)&pad[3 + h][8 + w0] = make_float4(res[g][4], res[g][5], res[g][6], res[g][7]);
    }
    __syncthreads();
    if (t < 64)       pad[67][4 + t] = pad[65][4 + t];
    else if (t < 128) { int y = t - 64; pad[3 + y][68] = pad[3 + y][66]; }
    else if (t == 128) pad[67][68] = pad[65][66];
    __syncthreads();

    const float* wdp = Wd + c * 64;
    float gc  = g3[c] * INVBN;
    float bcv = b3[c];
#pragma unroll
    for (int g = 0; g < 2; ++g) {
        int h = g * 32 + rr;
        float acc2[8];
#pragma unroll
        for (int p = 0; p < 8; ++p) acc2[p] = 0.f;
#pragma unroll
        for (int i = 0; i < 8; ++i) {
            float win[16];
            *(float4*)&win[0]  = *(const float4*)&pad[h + i][w0];
            *(float4*)&win[4]  = *(const float4*)&pad[h + i][w0 + 4];
            *(float4*)&win[8]  = *(const float4*)&pad[h + i][w0 + 8];
            *(float4*)&win[12] = *(const float4*)&pad[h + i][w0 + 12];
#pragma unroll
            for (int j = 0; j < 8; ++j) {
                float wv = wdp[i * 8 + j];
#pragma unroll
                for (int p = 0; p < 8; ++p)
                    acc2[p] = fmaf(wv, win[p + 1 + j], acc2[p]);
            }
        }
        us8v o8;
#pragma unroll
        for (int p = 0; p < 8; ++p) o8[p] = (short)f2bf(gc * acc2[p] + bcv);
        *(us8v*)&U[(size_t)bc * 4096 + h * 64 + w0] = o8;
    }
}

// ---------------------------------------------------------------------------
// U (B,512,4096) bf16 -> Ut (B,4096,512) bf16.  64p x 64c LDS tiles.
// ---------------------------------------------------------------------------
__global__ __launch_bounds__(256)
void transpose_cp_kernel(const unsigned short* __restrict__ U, unsigned short* __restrict__ Ut)
{
    int pt = blockIdx.x;               // p-tile 0..63
    int b  = blockIdx.y;
    const unsigned short* Ub = U + (size_t)b * 512 * 4096;
    unsigned short* Utb = Ut + (size_t)b * 4096 * 512;
    __shared__ unsigned short tile[64][72];
    int t = threadIdx.x;
    int p0 = pt * 64;

    for (int cc = 0; cc < 8; ++cc) {
        int c0 = cc * 64;
        __syncthreads();
        {
            int cl = t >> 2, px = (t & 3) * 16;
            const unsigned short* src = &Ub[(size_t)(c0 + cl) * 4096 + p0 + px];
            *(us8v*)&tile[cl][px]     = *(const us8v*)src;
            *(us8v*)&tile[cl][px + 8] = *(const us8v*)(src + 8);
        }
        __syncthreads();
        {
            int pl = t >> 2, cx = (t & 3) * 16;
            us8v o0, o1;
#pragma unroll
            for (int e = 0; e < 8; ++e) {
                o0[e] = tile[cx + e][pl];
                o1[e] = tile[cx + 8 + e][pl];
            }
            unsigned short* dst = &Utb[(size_t)(p0 + pl) * 512 + c0 + cx];
            *(us8v*)dst       = o0;
            *(us8v*)(dst + 8) = o1;
        }
    }
}

// ---------------------------------------------------------------------------
extern "C" void kernel_launch(void* const* d_in, const int* in_sizes, int n_in,
                              void* d_out, int out_size, void* d_ws, size_t ws_size,
                              hipStream_t stream)
{
    (void)in_sizes; (void)n_in; (void)out_size;
    const float* x     = (const float*)d_in[0];
    const float* w_lc1 = (const float*)d_in[1];
    const float* g1    = (const float*)d_in[2];
    const float* b1    = (const float*)d_in[3];
    const float* w_lc2 = (const float*)d_in[4];
    const float* g2    = (const float*)d_in[5];
    const float* b2    = (const float*)d_in[6];
    const float* w_qkv = (const float*)d_in[7];
    const float* rt    = (const float*)d_in[8];
    const float* w_dw  = (const float*)d_in[9];
    const float* g3    = (const float*)d_in[10];
    const float* b3    = (const float*)d_in[11];
    const float* w_pw  = (const float*)d_in[12];
    float* out = (float*)d_out;

    unsigned short* S        = (unsigned short*)d_ws;
    unsigned short* local_us = S;
    unsigned short* xt_us    = S + 16777216;
    unsigned short* attnO    = xt_us;                   // alias: attn out (bf16)
    unsigned short* u_us     = xt_us;                   // alias: U in-place over attnO
    unsigned short* wt3_us   = S + 34619392;
    unsigned short* wq_us    = S + 36978688;
    unsigned short* wpw_us   = S + 37765120;
    float*          bsum     = (float*)(S + 38027264);
    float*          biasM    = (float*)(S + 38028288);
    unsigned short* qkv_us   = S + 38552576;
    unsigned short* ut_us    = local_us;                // alias: Ut after local dead

    const bool full = ws_size >= (size_t)(38552576 + 50331648) * 2;  // 177.77 MB

    repack_kernel<<<dim3(9216), 256, 0, stream>>>(w_lc2, w_lc1, w_qkv, w_pw,
                                                  g1, g2, b1, b2, rt,
                                                  wt3_us, wq_us, wpw_us, bsum, biasM);
    pad_transpose_kernel<<<dim3(66, 8), 256, 0, stream>>>(x, xt_us);
    mfma_gemm256<9, true, unsigned short><<<dim3(16, 2, 8), 512, 0, stream>>>(
        xt_us, wt3_us, bsum, local_us, 512);

    if (full) {
        mfma_gemm256<1, true, unsigned short><<<dim3(16, 6, 8), 512, 0, stream>>>(
            xt_us, wq_us, nullptr, qkv_us, 1536);
        attn_mfma_kernel<<<dim3(256, 8), 256, 0, stream>>>(qkv_us, biasM, attnO);
    } else {
        for (int b = 0; b < 8; ++b) {
            mfma_gemm256<1, true, unsigned short><<<dim3(16, 6, 1), 512, 0, stream>>>(
                xt_us + (size_t)b * 4356 * 512, wq_us, nullptr, qkv_us, 1536);
            attn_mfma_kernel<<<dim3(256, 1), 256, 0, stream>>>(
                qkv_us, biasM, attnO + (size_t)b * 2097152);
        }
    }

    pooldw_kernel<<<dim3(4096), 256, 0, stream>>>(attnO, local_us, w_dw, g3, b3, u_us);
    transpose_cp_kernel<<<dim3(64, 8), 256, 0, stream>>>(u_us, ut_us);
    mfma_gemm256<1, false, float><<<dim3(16, 2, 8), 512, 0, stream>>>(
        ut_us, wpw_us, nullptr, out, 512);
}

// Round 16
// 465.373 us; speedup vs baseline: 1.1107x; 1.0020x over previous
//
#include <hip/hip_runtime.h>

#define INVBN 0.9999950000374997f       // 1/sqrt(1 + 1e-5)
#define ATT_SCALE 0.17677669529663687f  // 32^-0.5

typedef short bf16x8 __attribute__((ext_vector_type(8)));
typedef float f32x4  __attribute__((ext_vector_type(4)));
typedef unsigned short us8v __attribute__((ext_vector_type(8)));

#define AS1C(p) ((const __attribute__((address_space(1))) void*)(p))
#define AS3(p)  ((__attribute__((address_space(3))) void*)(p))

#define VMCNT_BARRIER(Nstr) do {                                   \
    asm volatile("s_waitcnt vmcnt(" Nstr ")" ::: "memory");        \
    __builtin_amdgcn_s_barrier(); } while (0)

__device__ __forceinline__ float bf2f(unsigned short u) {
    return __uint_as_float(((unsigned)u) << 16);
}
__device__ __forceinline__ unsigned short f2bf(float f) {
    unsigned u = __float_as_uint(f);
    u += 0x7FFFu + ((u >> 16) & 1u);        // RNE
    return (unsigned short)(u >> 16);
}

// ---------------------------------------------------------------------------
// Repack: Wt3[tap][m][k] bf16 (BN-folded conv3x3 + lc1 into center tap),
// Wq, Wpw bf16, bsum[m] = b1+b2, PLUS Swin bias in MFMA C-layout (merged).
// ---------------------------------------------------------------------------
__global__ __launch_bounds__(256)
void repack_kernel(const float* __restrict__ W2, const float* __restrict__ W1,
                   const float* __restrict__ Wq, const float* __restrict__ Wp,
                   const float* __restrict__ g1, const float* __restrict__ g2,
                   const float* __restrict__ b1, const float* __restrict__ b2,
                   const float* __restrict__ RT,
                   unsigned short* __restrict__ Wt, unsigned short* __restrict__ WqO,
                   unsigned short* __restrict__ WpO, float* __restrict__ bsum,
                   float* __restrict__ biasM)
{
    int i = blockIdx.x * 256 + threadIdx.x;
    if (i < 512) bsum[i] = b1[i] + b2[i];
    if (i < 786432) WqO[i] = f2bf(Wq[i]);
    if (i < 262144) WpO[i] = f2bf(Wp[i]);
    if (i < 16384) {                       // Swin bias in MFMA C-layout
        int h = i >> 10, rem = i & 1023;
        int frag = rem >> 6, lane = rem & 63;
        int fi = frag >> 2, fj = frag & 3;
        int q  = 16 * fj + (lane & 15);
        int kb = 16 * fi + ((lane >> 4) << 2);
        int yi = q >> 3, xi = q & 7;
        float4 o;
        float* op = (float*)&o;
#pragma unroll
        for (int r = 0; r < 4; ++r) {
            int j = kb + r;
            int ridx = (yi - (j >> 3) + 7) * 15 + (xi - (j & 7) + 7);
            op[r] = RT[ridx * 16 + h];
        }
        *(float4*)&biasM[(size_t)i * 4] = o;
    }
    if (i >= 2359296) return;
    int tap = i / 262144;
    int rem = i - tap * 262144;          // m*512 + k
    int m   = rem >> 9;
    float v = g2[m] * INVBN * W2[(size_t)rem * 9 + tap];
    if (tap == 4) v = fmaf(g1[m] * INVBN, W1[rem], v);
    Wt[i] = f2bf(v);
}

// ---------------------------------------------------------------------------
// x (B,512,64,64) f32 NCHW  ->  X_tp (B, 66*66, 512) bf16, zero borders.
// ---------------------------------------------------------------------------
__global__ __launch_bounds__(256)
void pad_transpose_kernel(const float* __restrict__ X, unsigned short* __restrict__ XT)
{
    int ph = blockIdx.x;      // 0..65
    int b  = blockIdx.y;
    int t  = threadIdx.x;
    unsigned short* rowbase = XT + ((size_t)b * 4356 + (size_t)ph * 66) * 512;
    uint4 z = make_uint4(0, 0, 0, 0);
    if (ph == 0 || ph == 65) {
        uint4* p4 = (uint4*)rowbase;                 // 66*512 elems = 4224 uint4
        for (int i = t; i < 4224; i += 256) p4[i] = z;
        return;
    }
    if (t < 64)       ((uint4*)rowbase)[t] = z;                  // pw = 0
    else if (t < 128) ((uint4*)(rowbase + 65 * 512))[t - 64] = z; // pw = 65

    int h = ph - 1;
    __shared__ float tile[64][65];
    const float* xb = X + (size_t)b * 512 * 4096 + h * 64;
    for (int cc = 0; cc < 8; ++cc) {
        int c0 = cc * 64;
        __syncthreads();
#pragma unroll
        for (int i = 0; i < 4; ++i) {
            int cl = i * 16 + (t >> 4);
            int w0 = (t & 15) * 4;
            *(float4*)&tile[cl][w0] =
                *(const float4*)&xb[(size_t)(c0 + cl) * 4096 + w0];
        }
        __syncthreads();
#pragma unroll
        for (int it = 0; it < 2; ++it) {
            int wl = it * 32 + (t >> 3);     // w = 0..63  -> pw = wl+1
            int cs = (t & 7) * 8;
            us8v v;
#pragma unroll
            for (int e = 0; e < 8; ++e) v[e] = f2bf(tile[cs + e][wl]);
            *(us8v*)&rowbase[(size_t)(1 + wl) * 512 + c0 + cs] = v;
        }
    }
}

// ---------------------------------------------------------------------------
// 256x256 MFMA GEMM (round-9 structure — best measured: conv 149.8 us,
// MfmaUtil 45.4, 0 bank conflicts).  8 waves, BK=32, 4 LDS buffers (128 KiB),
// vmcnt(8) counted ledger, chunk XOR-swizzle sigma(r) = ((r&15)>>1)&3
// (pre-swizzled global source + swizzled ds_read; linear gload_lds dest).
// A: PAD ? (B,66*66,512) padded-transposed : (B,4096,512) linear.
// Out: bf16 or f32 per OT.
// ---------------------------------------------------------------------------
template<int NTAPS, bool PAD, typename OT>
__global__ __launch_bounds__(512, 2)
void mfma_gemm256(const unsigned short* __restrict__ A,
                  const unsigned short* __restrict__ Bw,
                  const float* __restrict__ bias,
                  OT* __restrict__ Out, int M)
{
    __shared__ __align__(16) unsigned short ldsbuf[65536];   // 128 KiB

    const int t    = threadIdx.x;
    const int wid  = t >> 6, lane = t & 63;
    const int wr   = wid >> 2, wc = wid & 3;          // wave n-half / m-quarter
    const int lrow = lane & 15, lk = lane >> 4;
    const int n0 = blockIdx.x * 256;
    const int m0 = blockIdx.y * 256;
    const int b  = blockIdx.z;
    const unsigned short* Ab = A + (size_t)b * (PAD ? 4356 * 512 : 4096 * 512);
    OT* Ob = Out + (size_t)b * ((size_t)M * 4096);

    // --- staging source pointers: waves 0-3 stage A (256 spatial rows),
    //     waves 4-7 stage B (256 weight rows).  Source chunk pre-swizzled:
    //     LDS slot (rsub, ch) receives global chunk ch ^ sigma(rsub). ---
    const unsigned short* src[4];
    {
        int rsub = lane >> 2, ch = lane & 3;
        int chs  = ch ^ ((rsub >> 1) & 3);            // inverse swizzle on source
#pragma unroll
        for (int i = 0; i < 4; ++i) {
            if (wid < 4) {
                int p = n0 + (wid * 4 + i) * 16 + rsub;
                if (PAD) {
                    int h = p >> 6, w = p & 63;
                    src[i] = Ab + (size_t)((h + 1) * 66 + (w + 1)) * 512 + chs * 8;
                } else {
                    src[i] = Ab + (size_t)p * 512 + chs * 8;
                }
            } else {
                int m = m0 + ((wid - 4) * 4 + i) * 16 + rsub;
                src[i] = Bw + (size_t)m * 512 + chs * 8;
            }
        }
    }

    f32x4 acc[8][4] = {};

    // fragment chunk indices (swizzled reads)
    const int ck0 = (lk ^ ((lrow >> 1) & 3)) * 8;

    auto aScal = [&](int tt) -> int {
        if (NTAPS == 1) return tt * 32;
        int tap = tt >> 4;
        return (tap / 3 - 1) * (66 * 512) + (tap % 3 - 1) * 512 + (tt & 15) * 32;
    };
    auto bScal = [&](int tt) -> int {
        if (NTAPS == 1) return tt * 32;
        return (tt >> 4) * (M * 512) + (tt & 15) * 32;
    };
    auto STAGE = [&](int bufk, int aoff, int boff) {
        int off = (wid < 4) ? aoff : boff;
#pragma unroll
        for (int i = 0; i < 4; ++i)
            __builtin_amdgcn_global_load_lds(
                AS1C(src[i] + off),
                AS3(&ldsbuf[bufk * 16384 + (wid * 4 + i) * 512]), 16, 0, 0);
    };
    auto COMPUTE = [&](int bufk) {
        const unsigned short* Ak = &ldsbuf[bufk * 16384];
        const unsigned short* Bk = &ldsbuf[bufk * 16384 + 8192];
        bf16x8 af[8], bfr[4];
#pragma unroll
        for (int f = 0; f < 8; ++f)
            af[f] = *(const bf16x8*)&Ak[(wr * 128 + f * 16 + lrow) * 32 + ck0];
#pragma unroll
        for (int g = 0; g < 4; ++g)
            bfr[g] = *(const bf16x8*)&Bk[(wc * 64 + g * 16 + lrow) * 32 + ck0];
        __builtin_amdgcn_s_setprio(1);
#pragma unroll
        for (int f = 0; f < 8; ++f)
#pragma unroll
            for (int g = 0; g < 4; ++g)
                acc[f][g] = __builtin_amdgcn_mfma_f32_16x16x32_bf16(
                    af[f], bfr[g], acc[f][g], 0, 0, 0);
        __builtin_amdgcn_s_setprio(0);
    };

    constexpr int NT = NTAPS * 16;               // K-tiles of 32 (>= 16, mult of 4)

    // prologue: stage tiles 0,1,2; wait tile0 (outstanding: tiles 1,2 = 8)
    STAGE(0, aScal(0), bScal(0));
    STAGE(1, aScal(1), bScal(1));
    STAGE(2, aScal(2), bScal(2));
    VMCNT_BARRIER("8");

    // steady state: compute tile t (buf t%4), stage tile t+3 (buf (t+3)%4,
    // freed by the barrier ending tile t-1); end wait = tiles t+2,t+3 in
    // flight (8 loads) -> tile t+1 ready.
#pragma unroll 1
    for (int tb = 0; tb < NT - 4; tb += 4) {
        STAGE(3, aScal(tb + 3), bScal(tb + 3)); COMPUTE(0); VMCNT_BARRIER("8");
        STAGE(0, aScal(tb + 4), bScal(tb + 4)); COMPUTE(1); VMCNT_BARRIER("8");
        STAGE(1, aScal(tb + 5), bScal(tb + 5)); COMPUTE(2); VMCNT_BARRIER("8");
        STAGE(2, aScal(tb + 6), bScal(tb + 6)); COMPUTE(3); VMCNT_BARRIER("8");
    }
    // tail: tiles NT-4..NT-1 (NT ≡ 0 mod 4), drain 8 -> 4 -> 0
    STAGE(3, aScal(NT - 1), bScal(NT - 1)); COMPUTE(0); VMCNT_BARRIER("8");
    COMPUTE(1); VMCNT_BARRIER("4");
    COMPUTE(2); VMCNT_BARRIER("0");
    COMPUTE(3);

    // --- epilogue: bias + store (D: col m uses lrow, rows n use lk*4+r) ---
#pragma unroll
    for (int g = 0; g < 4; ++g) {
        int m = m0 + wc * 64 + g * 16 + lrow;
        float bv = bias ? bias[m] : 0.f;
        size_t mrow = (size_t)m * 4096;
#pragma unroll
        for (int f = 0; f < 8; ++f) {
            int nb = n0 + wr * 128 + f * 16 + lk * 4;
            f32x4 a4 = acc[f][g];
            if constexpr (sizeof(OT) == 2) {
                ushort4 o;
                o.x = f2bf(a4[0] + bv);
                o.y = f2bf(a4[1] + bv);
                o.z = f2bf(a4[2] + bv);
                o.w = f2bf(a4[3] + bv);
                *(ushort4*)&Ob[mrow + nb] = o;
            } else {
                *(float4*)&Ob[mrow + nb] =
                    make_float4(a4[0] + bv, a4[1] + bv, a4[2] + bv, a4[3] + bv);
            }
        }
    }
}

// ---------------------------------------------------------------------------
// MFMA window attention: 1 wave per (window, head), 4 waves/block.
// Output bf16 via per-wave LDS bounce -> coalesced 16B stores.
// ---------------------------------------------------------------------------
__global__ __launch_bounds__(256)
void attn_mfma_kernel(const unsigned short* __restrict__ QKV,
                      const float* __restrict__ biasM,
                      unsigned short* __restrict__ OutB)
{
    __shared__ short smem[4 * 9216];
    int t = threadIdx.x;
    int wv = t >> 6, lane = t & 63;
    int wing = blockIdx.x >> 2;
    int head = (blockIdx.x & 3) * 4 + wv;
    int b    = blockIdx.y;
    int hhi = wing >> 3, wwi = wing & 7;
    int sp0 = hhi * 512 + wwi * 8;
    int ch0 = head * 32;
    const unsigned short* Qg = QKV + (size_t)b * 1536 * 4096;

    short* Qtm = smem + wv * 9216;     // [64][36] token-major Q
    short* Ktm = Qtm + 2304;           // [64][36] token-major K
    short* Pq  = Qtm + 4608;           // [64][72] P (q-major); reused as O-bounce

    {
        int d  = lane & 31;
        int rb = lane >> 5;
#pragma unroll
        for (int i = 0; i < 4; ++i) {
            int r = rb + 2 * i;        // window row 0..7
            us8v q8 = *(const us8v*)&Qg[(size_t)(ch0 + d) * 4096 + sp0 + r * 64];
            us8v k8 = *(const us8v*)&Qg[(size_t)(512 + ch0 + d) * 4096 + sp0 + r * 64];
#pragma unroll
            for (int e = 0; e < 8; ++e) {
                Qtm[(r * 8 + e) * 36 + d] = (short)q8[e];
                Ktm[(r * 8 + e) * 36 + d] = (short)k8[e];
            }
        }
    }

    int lrow = lane & 15, lk = lane >> 4;

    bf16x8 kf[4], qf[4];
#pragma unroll
    for (int f = 0; f < 4; ++f) {
        kf[f] = *(const bf16x8*)&Ktm[(lrow + 16 * f) * 36 + lk * 8];
        qf[f] = *(const bf16x8*)&Qtm[(lrow + 16 * f) * 36 + lk * 8];
    }
    f32x4 s[4][4] = {};
#pragma unroll
    for (int fi = 0; fi < 4; ++fi)
#pragma unroll
        for (int fj = 0; fj < 4; ++fj)
            s[fi][fj] = __builtin_amdgcn_mfma_f32_16x16x32_bf16(
                kf[fi], qf[fj], s[fi][fj], 0, 0, 0);

    const float* bM = biasM + (size_t)head * 4096;
    float rs[4];
#pragma unroll
    for (int fj = 0; fj < 4; ++fj) {
        float v[4][4];
#pragma unroll
        for (int fi = 0; fi < 4; ++fi) {
            float4 bv = *(const float4*)&bM[((fi * 4 + fj) * 64 + lane) * 4];
            const float* bvp = (const float*)&bv;
#pragma unroll
            for (int r = 0; r < 4; ++r)
                v[fi][r] = fmaf(s[fi][fj][r], ATT_SCALE, bvp[r]);
        }
        float m = -1e30f;
#pragma unroll
        for (int fi = 0; fi < 4; ++fi)
#pragma unroll
            for (int r = 0; r < 4; ++r) m = fmaxf(m, v[fi][r]);
        m = fmaxf(m, __shfl_xor(m, 16));
        m = fmaxf(m, __shfl_xor(m, 32));
        float ev[4][4];
        float sum = 0.f;
#pragma unroll
        for (int fi = 0; fi < 4; ++fi)
#pragma unroll
            for (int r = 0; r < 4; ++r) {
                ev[fi][r] = __expf(v[fi][r] - m);
                sum += ev[fi][r];
            }
        sum += __shfl_xor(sum, 16);
        sum += __shfl_xor(sum, 32);
        rs[fj] = 1.f / sum;
#pragma unroll
        for (int fi = 0; fi < 4; ++fi) {
            unsigned p0 = (unsigned)f2bf(ev[fi][0]) | ((unsigned)f2bf(ev[fi][1]) << 16);
            unsigned p1 = (unsigned)f2bf(ev[fi][2]) | ((unsigned)f2bf(ev[fi][3]) << 16);
            *(uint2*)&Pq[(lrow + 16 * fj) * 72 + 16 * fi + lk * 4] = make_uint2(p0, p1);
        }
    }

    f32x4 o[2][4] = {};
#pragma unroll
    for (int ks = 0; ks < 2; ++ks) {
        bf16x8 vf[2], pf[4];
#pragma unroll
        for (int fid = 0; fid < 2; ++fid)
            vf[fid] = *(const bf16x8*)&Qg[(size_t)(1024 + ch0 + 16 * fid + lrow) * 4096
                                          + sp0 + (lk + 4 * ks) * 64];
#pragma unroll
        for (int fjq = 0; fjq < 4; ++fjq)
            pf[fjq] = *(const bf16x8*)&Pq[(lrow + 16 * fjq) * 72 + ks * 32 + lk * 8];
#pragma unroll
        for (int fid = 0; fid < 2; ++fid)
#pragma unroll
            for (int fjq = 0; fjq < 4; ++fjq)
                o[fid][fjq] = __builtin_amdgcn_mfma_f32_16x16x32_bf16(
                    vf[fid], pf[fjq], o[fid][fjq], 0, 0, 0);
    }

    // bounce O through the (now-dead) Pq region, then coalesced 16B stores.
#pragma unroll
    for (int fjq = 0; fjq < 4; ++fjq) {
        int q = lrow + 16 * fjq;
        float rr = rs[fjq];
#pragma unroll
        for (int fid = 0; fid < 2; ++fid) {
            int dch = 16 * fid + lk * 4;
#pragma unroll
            for (int r = 0; r < 4; ++r)
                Pq[(dch + r) * 72 + q] = (short)f2bf(o[fid][fjq][r] * rr);
        }
    }
    unsigned short* Out = OutB + (size_t)b * 512 * 4096;
#pragma unroll
    for (int j = 0; j < 4; ++j) {
        int dch  = lane & 31;
        int tokc = (lane >> 5) + 2 * j;    // window row 0..7
        us8v vv = *(const us8v*)&Pq[dch * 72 + tokc * 8];
        *(us8v*)&Out[(size_t)(ch0 + dch) * 4096 + sp0 + tokc * 64] = vv;
    }
}

// ---------------------------------------------------------------------------
// Fused pool(+local) + depthwise 8x8 + BN3: single 72x72 LDS tile,
// 8-wide pixel groups, b128 LDS traffic, dw weights via scalar loads.
// A bf16; U may alias A (per-plane read-before-write).
// ---------------------------------------------------------------------------
__global__ __launch_bounds__(256)
void pooldw_kernel(const unsigned short* __restrict__ A, const unsigned short* __restrict__ L,
                   const float* __restrict__ Wd,
                   const float* __restrict__ g3, const float* __restrict__ b3,
                   unsigned short* __restrict__ U)
{
    int bc = blockIdx.x;               // b*512 + c
    int c  = bc & 511;
    __shared__ float pad[72][72];      // 20.25 KB
    int t = threadIdx.x;
    float* pf = &pad[0][0];
#pragma unroll
    for (int i = 0; i < 21; ++i) {
        int e = i * 256 + t;
        if (e < 5184) pf[e] = 0.f;
    }
    __syncthreads();

    const unsigned short* ap = A + (size_t)bc * 4096;
#pragma unroll
    for (int i = 0; i < 4; ++i) {
        int idx = i * 256 + t;             // 1024 ushort4
        int y = idx >> 4, x4 = (idx & 15) * 4;
        ushort4 a4 = ((const ushort4*)ap)[idx];
        *(float4*)&pad[3 + y][4 + x4] =
            make_float4(bf2f(a4.x), bf2f(a4.y), bf2f(a4.z), bf2f(a4.w));
    }
    if (t < 64)       pad[67][4 + t] = bf2f(ap[62 * 64 + t]);
    else if (t < 128) { int y = t - 64; pad[3 + y][68] = bf2f(ap[y * 64 + 62]); }
    else if (t == 128) pad[67][68] = bf2f(ap[62 * 64 + 62]);
    __syncthreads();

    const unsigned short* lp = L + (size_t)bc * 4096;
    int u  = t & 7, rr = t >> 3;       // 8 w-groups x 32 row-phases
    int w0 = u * 8;
    float res[2][8];
#pragma unroll
    for (int g = 0; g < 2; ++g) {
        int h = g * 32 + rr;
        float4 sxlo = make_float4(0.f, 0.f, 0.f, 0.f);
        float4 sxhi = make_float4(0.f, 0.f, 0.f, 0.f);
#pragma unroll
        for (int i = 0; i < 8; ++i) {
            float4 a = *(const float4*)&pad[h + i][4 + w0];
            float4 bq = *(const float4*)&pad[h + i][8 + w0];
            sxlo.x += a.x; sxlo.y += a.y; sxlo.z += a.z; sxlo.w += a.w;
            sxhi.x += bq.x; sxhi.y += bq.y; sxhi.z += bq.z; sxhi.w += bq.w;
        }
        float sx[8] = {sxlo.x, sxlo.y, sxlo.z, sxlo.w, sxhi.x, sxhi.y, sxhi.z, sxhi.w};
        float win[16];
        *(float4*)&win[0]  = *(const float4*)&pad[3 + h][w0];
        *(float4*)&win[4]  = *(const float4*)&pad[3 + h][w0 + 4];
        *(float4*)&win[8]  = *(const float4*)&pad[3 + h][w0 + 8];
        *(float4*)&win[12] = *(const float4*)&pad[3 + h][w0 + 12];
        us8v l8 = *(const us8v*)&lp[h * 64 + w0];
#pragma unroll
        for (int p = 0; p < 8; ++p) {
            float sy = 0.f;
#pragma unroll
            for (int i = 1; i <= 8; ++i) sy += win[p + i];
            res[g][p] = fmaf(0.125f, sx[p] + sy, bf2f((unsigned short)l8[p]));
        }
    }
    __syncthreads();

#pragma unroll
    for (int g = 0; g < 2; ++g) {
        int h = g * 32 + rr;
        *(float4*)&pad[3 + h][4 + w0] = make_float4(res[g][0], res[g][1], res[g][2], res[g][3]);
        *(float4*)&pad[3 + h][8 + w0] = make_float4(res[g][4], res[g][5], res[g][6], res[g][7]);
    }
    __syncthreads();
    if (t < 64)       pad[67][4 + t] = pad[65][4 + t];
    else if (t < 128) { int y = t - 64; pad[3 + y][68] = pad[3 + y][66]; }
    else if (t == 128) pad[67][68] = pad[65][66];
    __syncthreads();

    const float* wdp = Wd + c * 64;
    float gc  = g3[c] * INVBN;
    float bcv = b3[c];
#pragma unroll
    for (int g = 0; g < 2; ++g) {
        int h = g * 32 + rr;
        float acc2[8];
#pragma unroll
        for (int p = 0; p < 8; ++p) acc2[p] = 0.f;
#pragma unroll
        for (int i = 0; i < 8; ++i) {
            float win[16];
            *(float4*)&win[0]  = *(const float4*)&pad[h + i][w0];
            *(float4*)&win[4]  = *(const float4*)&pad[h + i][w0 + 4];
            *(float4*)&win[8]  = *(const float4*)&pad[h + i][w0 + 8];
            *(float4*)&win[12] = *(const float4*)&pad[h + i][w0 + 12];
#pragma unroll
            for (int j = 0; j < 8; ++j) {
                float wv = wdp[i * 8 + j];
#pragma unroll
                for (int p = 0; p < 8; ++p)
                    acc2[p] = fmaf(wv, win[p + 1 + j], acc2[p]);
            }
        }
        us8v o8;
#pragma unroll
        for (int p = 0; p < 8; ++p) o8[p] = (short)f2bf(gc * acc2[p] + bcv);
        *(us8v*)&U[(size_t)bc * 4096 + h * 64 + w0] = o8;
    }
}

// ---------------------------------------------------------------------------
// U (B,512,4096) bf16 -> Ut (B,4096,512) bf16.  64p x 64c LDS tiles.
// ---------------------------------------------------------------------------
__global__ __launch_bounds__(256)
void transpose_cp_kernel(const unsigned short* __restrict__ U, unsigned short* __restrict__ Ut)
{
    int pt = blockIdx.x;               // p-tile 0..63
    int b  = blockIdx.y;
    const unsigned short* Ub = U + (size_t)b * 512 * 4096;
    unsigned short* Utb = Ut + (size_t)b * 4096 * 512;
    __shared__ unsigned short tile[64][72];
    int t = threadIdx.x;
    int p0 = pt * 64;

    for (int cc = 0; cc < 8; ++cc) {
        int c0 = cc * 64;
        __syncthreads();
        {
            int cl = t >> 2, px = (t & 3) * 16;
            const unsigned short* src = &Ub[(size_t)(c0 + cl) * 4096 + p0 + px];
            *(us8v*)&tile[cl][px]     = *(const us8v*)src;
            *(us8v*)&tile[cl][px + 8] = *(const us8v*)(src + 8);
        }
        __syncthreads();
        {
            int pl = t >> 2, cx = (t & 3) * 16;
            us8v o0, o1;
#pragma unroll
            for (int e = 0; e < 8; ++e) {
                o0[e] = tile[cx + e][pl];
                o1[e] = tile[cx + 8 + e][pl];
            }
            unsigned short* dst = &Utb[(size_t)(p0 + pl) * 512 + c0 + cx];
            *(us8v*)dst       = o0;
            *(us8v*)(dst + 8) = o1;
        }
    }
}

// ---------------------------------------------------------------------------
extern "C" void kernel_launch(void* const* d_in, const int* in_sizes, int n_in,
                              void* d_out, int out_size, void* d_ws, size_t ws_size,
                              hipStream_t stream)
{
    (void)in_sizes; (void)n_in; (void)out_size;
    const float* x     = (const float*)d_in[0];
    const float* w_lc1 = (const float*)d_in[1];
    const float* g1    = (const float*)d_in[2];
    const float* b1    = (const float*)d_in[3];
    const float* w_lc2 = (const float*)d_in[4];
    const float* g2    = (const float*)d_in[5];
    const float* b2    = (const float*)d_in[6];
    const float* w_qkv = (const float*)d_in[7];
    const float* rt    = (const float*)d_in[8];
    const float* w_dw  = (const float*)d_in[9];
    const float* g3    = (const float*)d_in[10];
    const float* b3    = (const float*)d_in[11];
    const float* w_pw  = (const float*)d_in[12];
    float* out = (float*)d_out;

    unsigned short* S        = (unsigned short*)d_ws;
    unsigned short* local_us = S;
    unsigned short* xt_us    = S + 16777216;
    unsigned short* attnO    = xt_us;                   // alias: attn out (bf16)
    unsigned short* u_us     = xt_us;                   // alias: U in-place over attnO
    unsigned short* wt3_us   = S + 34619392;
    unsigned short* wq_us    = S + 36978688;
    unsigned short* wpw_us   = S + 37765120;
    float*          bsum     = (float*)(S + 38027264);
    float*          biasM    = (float*)(S + 38028288);
    unsigned short* qkv_us   = S + 38552576;
    unsigned short* ut_us    = local_us;                // alias: Ut after local dead

    const bool full = ws_size >= (size_t)(38552576 + 50331648) * 2;  // 177.77 MB

    repack_kernel<<<dim3(9216), 256, 0, stream>>>(w_lc2, w_lc1, w_qkv, w_pw,
                                                  g1, g2, b1, b2, rt,
                                                  wt3_us, wq_us, wpw_us, bsum, biasM);
    pad_transpose_kernel<<<dim3(66, 8), 256, 0, stream>>>(x, xt_us);
    mfma_gemm256<9, true, unsigned short><<<dim3(16, 2, 8), 512, 0, stream>>>(
        xt_us, wt3_us, bsum, local_us, 512);

    if (full) {
        mfma_gemm256<1, true, unsigned short><<<dim3(16, 6, 8), 512, 0, stream>>>(
            xt_us, wq_us, nullptr, qkv_us, 1536);
        attn_mfma_kernel<<<dim3(256, 8), 256, 0, stream>>>(qkv_us, biasM, attnO);
    } else {
        for (int b = 0; b < 8; ++b) {
            mfma_gemm256<1, true, unsigned short><<<dim3(16, 6, 1), 512, 0, stream>>>(
                xt_us + (size_t)b * 4356 * 512, wq_us, nullptr, qkv_us, 1536);
            attn_mfma_kernel<<<dim3(256, 1), 256, 0, stream>>>(
                qkv_us, biasM, attnO + (size_t)b * 2097152);
        }
    }

    pooldw_kernel<<<dim3(4096), 256, 0, stream>>>(attnO, local_us, w_dw, g3, b3, u_us);
    transpose_cp_kernel<<<dim3(64, 8), 256, 0, stream>>>(u_us, ut_us);
    mfma_gemm256<1, false, float><<<dim3(16, 2, 8), 512, 0, stream>>>(
        ut_us, wpw_us, nullptr, out, 512);
}

// Round 17
// 455.877 us; speedup vs baseline: 1.1338x; 1.0208x over previous
//
#include <hip/hip_runtime.h>

#define INVBN 0.9999950000374997f       // 1/sqrt(1 + 1e-5)
#define ATT_SCALE 0.17677669529663687f  // 32^-0.5

typedef short bf16x8 __attribute__((ext_vector_type(8)));
typedef float f32x4  __attribute__((ext_vector_type(4)));
typedef unsigned short us8v __attribute__((ext_vector_type(8)));

#define AS1C(p) ((const __attribute__((address_space(1))) void*)(p))
#define AS3(p)  ((__attribute__((address_space(3))) void*)(p))

__device__ __forceinline__ float bf2f(unsigned short u) {
    return __uint_as_float(((unsigned)u) << 16);
}
__device__ __forceinline__ unsigned short f2bf(float f) {
    unsigned u = __float_as_uint(f);
    u += 0x7FFFu + ((u >> 16) & 1u);        // RNE
    return (unsigned short)(u >> 16);
}

// ---------------------------------------------------------------------------
// Repack: Wt3[tap][m][k] bf16 (BN-folded conv3x3 + lc1 into center tap),
// Wq, Wpw bf16, bsum[m] = b1+b2, PLUS Swin bias in MFMA C-layout (merged).
// ---------------------------------------------------------------------------
__global__ __launch_bounds__(256)
void repack_kernel(const float* __restrict__ W2, const float* __restrict__ W1,
                   const float* __restrict__ Wq, const float* __restrict__ Wp,
                   const float* __restrict__ g1, const float* __restrict__ g2,
                   const float* __restrict__ b1, const float* __restrict__ b2,
                   const float* __restrict__ RT,
                   unsigned short* __restrict__ Wt, unsigned short* __restrict__ WqO,
                   unsigned short* __restrict__ WpO, float* __restrict__ bsum,
                   float* __restrict__ biasM)
{
    int i = blockIdx.x * 256 + threadIdx.x;
    if (i < 512) bsum[i] = b1[i] + b2[i];
    if (i < 786432) WqO[i] = f2bf(Wq[i]);
    if (i < 262144) WpO[i] = f2bf(Wp[i]);
    if (i < 16384) {                       // Swin bias in MFMA C-layout
        int h = i >> 10, rem = i & 1023;
        int frag = rem >> 6, lane = rem & 63;
        int fi = frag >> 2, fj = frag & 3;
        int q  = 16 * fj + (lane & 15);
        int kb = 16 * fi + ((lane >> 4) << 2);
        int yi = q >> 3, xi = q & 7;
        float4 o;
        float* op = (float*)&o;
#pragma unroll
        for (int r = 0; r < 4; ++r) {
            int j = kb + r;
            int ridx = (yi - (j >> 3) + 7) * 15 + (xi - (j & 7) + 7);
            op[r] = RT[ridx * 16 + h];
        }
        *(float4*)&biasM[(size_t)i * 4] = o;
    }
    if (i >= 2359296) return;
    int tap = i / 262144;
    int rem = i - tap * 262144;          // m*512 + k
    int m   = rem >> 9;
    float v = g2[m] * INVBN * W2[(size_t)rem * 9 + tap];
    if (tap == 4) v = fmaf(g1[m] * INVBN, W1[rem], v);
    Wt[i] = f2bf(v);
}

// ---------------------------------------------------------------------------
// x (B,512,64,64) f32 NCHW  ->  X_tp (B, 66*66, 512) bf16, zero borders.
// ---------------------------------------------------------------------------
__global__ __launch_bounds__(256)
void pad_transpose_kernel(const float* __restrict__ X, unsigned short* __restrict__ XT)
{
    int ph = blockIdx.x;      // 0..65
    int b  = blockIdx.y;
    int t  = threadIdx.x;
    unsigned short* rowbase = XT + ((size_t)b * 4356 + (size_t)ph * 66) * 512;
    uint4 z = make_uint4(0, 0, 0, 0);
    if (ph == 0 || ph == 65) {
        uint4* p4 = (uint4*)rowbase;                 // 66*512 elems = 4224 uint4
        for (int i = t; i < 4224; i += 256) p4[i] = z;
        return;
    }
    if (t < 64)       ((uint4*)rowbase)[t] = z;                  // pw = 0
    else if (t < 128) ((uint4*)(rowbase + 65 * 512))[t - 64] = z; // pw = 65

    int h = ph - 1;
    __shared__ float tile[64][65];
    const float* xb = X + (size_t)b * 512 * 4096 + h * 64;
    for (int cc = 0; cc < 8; ++cc) {
        int c0 = cc * 64;
        __syncthreads();
#pragma unroll
        for (int i = 0; i < 4; ++i) {
            int cl = i * 16 + (t >> 4);
            int w0 = (t & 15) * 4;
            *(float4*)&tile[cl][w0] =
                *(const float4*)&xb[(size_t)(c0 + cl) * 4096 + w0];
        }
        __syncthreads();
#pragma unroll
        for (int it = 0; it < 2; ++it) {
            int wl = it * 32 + (t >> 3);     // w = 0..63  -> pw = wl+1
            int cs = (t & 7) * 8;
            us8v v;
#pragma unroll
            for (int e = 0; e < 8; ++e) v[e] = f2bf(tile[cs + e][wl]);
            *(us8v*)&rowbase[(size_t)(1 + wl) * 512 + c0 + cs] = v;
        }
    }
}

// ---------------------------------------------------------------------------
// 256x256 MFMA GEMM, BK=64 double-buffer: 64 MFMA + 24 ds_read per barrier
// region (2x the round-9 region — tests the region-size-limits-pipelining
// hypothesis).  8 waves, 2 x 64 KiB buffers, counted vmcnt(8) ledger
// (STAGE t+1 -> outstanding 16 -> vmcnt(8) = tile t complete).
// Chunk XOR-swizzle sigma(row) = row&7 over 8 chunks/row (pre-swizzled global
// source + swizzled ds_read; linear gload_lds dest) -> 2-way banks = free.
// A: PAD ? (B,66*66,512) padded-transposed : (B,4096,512) linear.
// ---------------------------------------------------------------------------
template<int NTAPS, bool PAD, typename OT>
__global__ __launch_bounds__(512, 1)
void mfma_gemm256(const unsigned short* __restrict__ A,
                  const unsigned short* __restrict__ Bw,
                  const float* __restrict__ bias,
                  OT* __restrict__ Out, int M)
{
    __shared__ __align__(16) unsigned short ldsbuf[65536];   // 2 x (32K A + 32K B)

    const int t    = threadIdx.x;
    const int wid  = t >> 6, lane = t & 63;
    const int wr   = wid >> 2, wc = wid & 3;          // wave n-half / m-quarter
    const int lrow = lane & 15, lk = lane >> 4;
    const int n0 = blockIdx.x * 256;
    const int m0 = blockIdx.y * 256;
    const int b  = blockIdx.z;
    const unsigned short* Ab = A + (size_t)b * (PAD ? 4356 * 512 : 4096 * 512);
    OT* Ob = Out + (size_t)b * ((size_t)M * 4096);

    // --- staging: waves 0-3 stage A rows [wid*64, wid*64+64), waves 4-7 the
    //     matching B rows.  lane -> (rsub = lane>>3, ch = lane&7); source
    //     chunk pre-swizzled chs = ch ^ rsub  (row&7 == rsub for all loads).
    const unsigned short* src[8];
    {
        int rsub = lane >> 3, ch = lane & 7;
        int chs  = ch ^ rsub;
#pragma unroll
        for (int i = 0; i < 8; ++i) {
            int row = (wid & 3) * 64 + i * 8 + rsub;
            if (wid < 4) {
                int p = n0 + row;
                if (PAD) {
                    int h = p >> 6, w = p & 63;
                    src[i] = Ab + (size_t)((h + 1) * 66 + (w + 1)) * 512 + chs * 8;
                } else {
                    src[i] = Ab + (size_t)p * 512 + chs * 8;
                }
            } else {
                src[i] = Bw + (size_t)(m0 + row) * 512 + chs * 8;
            }
        }
    }
    // wave-uniform LDS dest base (HW adds lane*16B): A half or B half
    const int dbase = (wid >> 2) * 16384 + (wid & 3) * 4096;

    f32x4 acc[8][4] = {};

    auto aScal = [&](int tt) -> int {
        if (NTAPS == 1) return tt * 64;
        int tap = tt >> 3;
        return (tap / 3 - 1) * (66 * 512) + (tap % 3 - 1) * 512 + (tt & 7) * 64;
    };
    auto bScal = [&](int tt) -> int {
        if (NTAPS == 1) return tt * 64;
        return (tt >> 3) * (M * 512) + (tt & 7) * 64;
    };
    auto STAGE = [&](int bufk, int aoff, int boff) {
        int off = (wid < 4) ? aoff : boff;
#pragma unroll
        for (int i = 0; i < 8; ++i)
            __builtin_amdgcn_global_load_lds(
                AS1C(src[i] + off),
                AS3(&ldsbuf[bufk * 32768 + dbase + i * 512]), 16, 0, 0);
    };
    // COMPUTE: one barrier-free region of 24 ds_read_b128 + 64 MFMA.
    auto COMPUTE = [&](int bufk) {
        const unsigned short* Ak = &ldsbuf[bufk * 32768];
        const unsigned short* Bk = &ldsbuf[bufk * 32768 + 16384];
        __builtin_amdgcn_s_setprio(1);
#pragma unroll
        for (int kk = 0; kk < 2; ++kk) {
            const int ck = ((kk * 4 + lk) ^ (lrow & 7)) * 8;
            bf16x8 af[8], bfr[4];
#pragma unroll
            for (int f = 0; f < 8; ++f)
                af[f] = *(const bf16x8*)&Ak[(wr * 128 + f * 16 + lrow) * 64 + ck];
#pragma unroll
            for (int g = 0; g < 4; ++g)
                bfr[g] = *(const bf16x8*)&Bk[(wc * 64 + g * 16 + lrow) * 64 + ck];
#pragma unroll
            for (int f = 0; f < 8; ++f)
#pragma unroll
                for (int g = 0; g < 4; ++g)
                    acc[f][g] = __builtin_amdgcn_mfma_f32_16x16x32_bf16(
                        af[f], bfr[g], acc[f][g], 0, 0, 0);
        }
        __builtin_amdgcn_s_setprio(0);
    };

    constexpr int NT = (NTAPS == 1) ? 8 : 72;        // K-tiles of 64

    STAGE(0, aScal(0), bScal(0));
#pragma unroll 1
    for (int tt = 0; tt < NT; ++tt) {
        if (tt + 1 < NT) {
            STAGE((tt + 1) & 1, aScal(tt + 1), bScal(tt + 1));
            // outstanding: tile tt (8) + tile tt+1 (8) -> wait tile tt done
            asm volatile("s_waitcnt vmcnt(8)" ::: "memory");
        } else {
            asm volatile("s_waitcnt vmcnt(0)" ::: "memory");
        }
        __builtin_amdgcn_s_barrier();
        COMPUTE(tt & 1);
        __builtin_amdgcn_s_barrier();   // reads done before next STAGE reuses buf
    }

    // --- epilogue: bias + store (D: col m uses lrow, rows n use lk*4+r) ---
#pragma unroll
    for (int g = 0; g < 4; ++g) {
        int m = m0 + wc * 64 + g * 16 + lrow;
        float bv = bias ? bias[m] : 0.f;
        size_t mrow = (size_t)m * 4096;
#pragma unroll
        for (int f = 0; f < 8; ++f) {
            int nb = n0 + wr * 128 + f * 16 + lk * 4;
            f32x4 a4 = acc[f][g];
            if constexpr (sizeof(OT) == 2) {
                ushort4 o;
                o.x = f2bf(a4[0] + bv);
                o.y = f2bf(a4[1] + bv);
                o.z = f2bf(a4[2] + bv);
                o.w = f2bf(a4[3] + bv);
                *(ushort4*)&Ob[mrow + nb] = o;
            } else {
                *(float4*)&Ob[mrow + nb] =
                    make_float4(a4[0] + bv, a4[1] + bv, a4[2] + bv, a4[3] + bv);
            }
        }
    }
}

// ---------------------------------------------------------------------------
// MFMA window attention: 1 wave per (window, head), 4 waves/block.
// Output bf16 via per-wave LDS bounce -> coalesced 16B stores.
// ---------------------------------------------------------------------------
__global__ __launch_bounds__(256)
void attn_mfma_kernel(const unsigned short* __restrict__ QKV,
                      const float* __restrict__ biasM,
                      unsigned short* __restrict__ OutB)
{
    __shared__ short smem[4 * 9216];
    int t = threadIdx.x;
    int wv = t >> 6, lane = t & 63;
    int wing = blockIdx.x >> 2;
    int head = (blockIdx.x & 3) * 4 + wv;
    int b    = blockIdx.y;
    int hhi = wing >> 3, wwi = wing & 7;
    int sp0 = hhi * 512 + wwi * 8;
    int ch0 = head * 32;
    const unsigned short* Qg = QKV + (size_t)b * 1536 * 4096;

    short* Qtm = smem + wv * 9216;     // [64][36] token-major Q
    short* Ktm = Qtm + 2304;           // [64][36] token-major K
    short* Pq  = Qtm + 4608;           // [64][72] P (q-major); reused as O-bounce

    {
        int d  = lane & 31;
        int rb = lane >> 5;
#pragma unroll
        for (int i = 0; i < 4; ++i) {
            int r = rb + 2 * i;        // window row 0..7
            us8v q8 = *(const us8v*)&Qg[(size_t)(ch0 + d) * 4096 + sp0 + r * 64];
            us8v k8 = *(const us8v*)&Qg[(size_t)(512 + ch0 + d) * 4096 + sp0 + r * 64];
#pragma unroll
            for (int e = 0; e < 8; ++e) {
                Qtm[(r * 8 + e) * 36 + d] = (short)q8[e];
                Ktm[(r * 8 + e) * 36 + d] = (short)k8[e];
            }
        }
    }

    int lrow = lane & 15, lk = lane >> 4;

    bf16x8 kf[4], qf[4];
#pragma unroll
    for (int f = 0; f < 4; ++f) {
        kf[f] = *(const bf16x8*)&Ktm[(lrow + 16 * f) * 36 + lk * 8];
        qf[f] = *(const bf16x8*)&Qtm[(lrow + 16 * f) * 36 + lk * 8];
    }
    f32x4 s[4][4] = {};
#pragma unroll
    for (int fi = 0; fi < 4; ++fi)
#pragma unroll
        for (int fj = 0; fj < 4; ++fj)
            s[fi][fj] = __builtin_amdgcn_mfma_f32_16x16x32_bf16(
                kf[fi], qf[fj], s[fi][fj], 0, 0, 0);

    const float* bM = biasM + (size_t)head * 4096;
    float rs[4];
#pragma unroll
    for (int fj = 0; fj < 4; ++fj) {
        float v[4][4];
#pragma unroll
        for (int fi = 0; fi < 4; ++fi) {
            float4 bv = *(const float4*)&bM[((fi * 4 + fj) * 64 + lane) * 4];
            const float* bvp = (const float*)&bv;
#pragma unroll
            for (int r = 0; r < 4; ++r)
                v[fi][r] = fmaf(s[fi][fj][r], ATT_SCALE, bvp[r]);
        }
        float m = -1e30f;
#pragma unroll
        for (int fi = 0; fi < 4; ++fi)
#pragma unroll
            for (int r = 0; r < 4; ++r) m = fmaxf(m, v[fi][r]);
        m = fmaxf(m, __shfl_xor(m, 16));
        m = fmaxf(m, __shfl_xor(m, 32));
        float ev[4][4];
        float sum = 0.f;
#pragma unroll
        for (int fi = 0; fi < 4; ++fi)
#pragma unroll
            for (int r = 0; r < 4; ++r) {
                ev[fi][r] = __expf(v[fi][r] - m);
                sum += ev[fi][r];
            }
        sum += __shfl_xor(sum, 16);
        sum += __shfl_xor(sum, 32);
        rs[fj] = 1.f / sum;
#pragma unroll
        for (int fi = 0; fi < 4; ++fi) {
            unsigned p0 = (unsigned)f2bf(ev[fi][0]) | ((unsigned)f2bf(ev[fi][1]) << 16);
            unsigned p1 = (unsigned)f2bf(ev[fi][2]) | ((unsigned)f2bf(ev[fi][3]) << 16);
            *(uint2*)&Pq[(lrow + 16 * fj) * 72 + 16 * fi + lk * 4] = make_uint2(p0, p1);
        }
    }

    f32x4 o[2][4] = {};
#pragma unroll
    for (int ks = 0; ks < 2; ++ks) {
        bf16x8 vf[2], pf[4];
#pragma unroll
        for (int fid = 0; fid < 2; ++fid)
            vf[fid] = *(const bf16x8*)&Qg[(size_t)(1024 + ch0 + 16 * fid + lrow) * 4096
                                          + sp0 + (lk + 4 * ks) * 64];
#pragma unroll
        for (int fjq = 0; fjq < 4; ++fjq)
            pf[fjq] = *(const bf16x8*)&Pq[(lrow + 16 * fjq) * 72 + ks * 32 + lk * 8];
#pragma unroll
        for (int fid = 0; fid < 2; ++fid)
#pragma unroll
            for (int fjq = 0; fjq < 4; ++fjq)
                o[fid][fjq] = __builtin_amdgcn_mfma_f32_16x16x32_bf16(
                    vf[fid], pf[fjq], o[fid][fjq], 0, 0, 0);
    }

    // bounce O through the (now-dead) Pq region, then coalesced 16B stores.
#pragma unroll
    for (int fjq = 0; fjq < 4; ++fjq) {
        int q = lrow + 16 * fjq;
        float rr = rs[fjq];
#pragma unroll
        for (int fid = 0; fid < 2; ++fid) {
            int dch = 16 * fid + lk * 4;
#pragma unroll
            for (int r = 0; r < 4; ++r)
                Pq[(dch + r) * 72 + q] = (short)f2bf(o[fid][fjq][r] * rr);
        }
    }
    unsigned short* Out = OutB + (size_t)b * 512 * 4096;
#pragma unroll
    for (int j = 0; j < 4; ++j) {
        int dch  = lane & 31;
        int tokc = (lane >> 5) + 2 * j;    // window row 0..7
        us8v vv = *(const us8v*)&Pq[dch * 72 + tokc * 8];
        *(us8v*)&Out[(size_t)(ch0 + dch) * 4096 + sp0 + tokc * 64] = vv;
    }
}

// ---------------------------------------------------------------------------
// Fused pool(+local) + depthwise 8x8 + BN3: single 72x72 LDS tile,
// 8-wide pixel groups, b128 LDS traffic, dw weights via scalar loads.
// A bf16; U may alias A (per-plane read-before-write).
// ---------------------------------------------------------------------------
__global__ __launch_bounds__(256)
void pooldw_kernel(const unsigned short* __restrict__ A, const unsigned short* __restrict__ L,
                   const float* __restrict__ Wd,
                   const float* __restrict__ g3, const float* __restrict__ b3,
                   unsigned short* __restrict__ U)
{
    int bc = blockIdx.x;               // b*512 + c
    int c  = bc & 511;
    __shared__ float pad[72][72];      // 20.25 KB
    int t = threadIdx.x;
    float* pf = &pad[0][0];
#pragma unroll
    for (int i = 0; i < 21; ++i) {
        int e = i * 256 + t;
        if (e < 5184) pf[e] = 0.f;
    }
    __syncthreads();

    const unsigned short* ap = A + (size_t)bc * 4096;
#pragma unroll
    for (int i = 0; i < 4; ++i) {
        int idx = i * 256 + t;             // 1024 ushort4
        int y = idx >> 4, x4 = (idx & 15) * 4;
        ushort4 a4 = ((const ushort4*)ap)[idx];
        *(float4*)&pad[3 + y][4 + x4] =
            make_float4(bf2f(a4.x), bf2f(a4.y), bf2f(a4.z), bf2f(a4.w));
    }
    if (t < 64)       pad[67][4 + t] = bf2f(ap[62 * 64 + t]);
    else if (t < 128) { int y = t - 64; pad[3 + y][68] = bf2f(ap[y * 64 + 62]); }
    else if (t == 128) pad[67][68] = bf2f(ap[62 * 64 + 62]);
    __syncthreads();

    const unsigned short* lp = L + (size_t)bc * 4096;
    int u  = t & 7, rr = t >> 3;       // 8 w-groups x 32 row-phases
    int w0 = u * 8;
    float res[2][8];
#pragma unroll
    for (int g = 0; g < 2; ++g) {
        int h = g * 32 + rr;
        float4 sxlo = make_float4(0.f, 0.f, 0.f, 0.f);
        float4 sxhi = make_float4(0.f, 0.f, 0.f, 0.f);
#pragma unroll
        for (int i = 0; i < 8; ++i) {
            float4 a = *(const float4*)&pad[h + i][4 + w0];
            float4 bq = *(const float4*)&pad[h + i][8 + w0];
            sxlo.x += a.x; sxlo.y += a.y; sxlo.z += a.z; sxlo.w += a.w;
            sxhi.x += bq.x; sxhi.y += bq.y; sxhi.z += bq.z; sxhi.w += bq.w;
        }
        float sx[8] = {sxlo.x, sxlo.y, sxlo.z, sxlo.w, sxhi.x, sxhi.y, sxhi.z, sxhi.w};
        float win[16];
        *(float4*)&win[0]  = *(const float4*)&pad[3 + h][w0];
        *(float4*)&win[4]  = *(const float4*)&pad[3 + h][w0 + 4];
        *(float4*)&win[8]  = *(const float4*)&pad[3 + h][w0 + 8];
        *(float4*)&win[12] = *(const float4*)&pad[3 + h][w0 + 12];
        us8v l8 = *(const us8v*)&lp[h * 64 + w0];
#pragma unroll
        for (int p = 0; p < 8; ++p) {
            float sy = 0.f;
#pragma unroll
            for (int i = 1; i <= 8; ++i) sy += win[p + i];
            res[g][p] = fmaf(0.125f, sx[p] + sy, bf2f((unsigned short)l8[p]));
        }
    }
    __syncthreads();

#pragma unroll
    for (int g = 0; g < 2; ++g) {
        int h = g * 32 + rr;
        *(float4*)&pad[3 + h][4 + w0] = make_float4(res[g][0], res[g][1], res[g][2], res[g][3]);
        *(float4*)&pad[3 + h][8 + w0] = make_float4(res[g][4], res[g][5], res[g][6], res[g][7]);
    }
    __syncthreads();
    if (t < 64)       pad[67][4 + t] = pad[65][4 + t];
    else if (t < 128) { int y = t - 64; pad[3 + y][68] = pad[3 + y][66]; }
    else if (t == 128) pad[67][68] = pad[65][66];
    __syncthreads();

    const float* wdp = Wd + c * 64;
    float gc  = g3[c] * INVBN;
    float bcv = b3[c];
#pragma unroll
    for (int g = 0; g < 2; ++g) {
        int h = g * 32 + rr;
        float acc2[8];
#pragma unroll
        for (int p = 0; p < 8; ++p) acc2[p] = 0.f;
#pragma unroll
        for (int i = 0; i < 8; ++i) {
            float win[16];
            *(float4*)&win[0]  = *(const float4*)&pad[h + i][w0];
            *(float4*)&win[4]  = *(const float4*)&pad[h + i][w0 + 4];
            *(float4*)&win[8]  = *(const float4*)&pad[h + i][w0 + 8];
            *(float4*)&win[12] = *(const float4*)&pad[h + i][w0 + 12];
#pragma unroll
            for (int j = 0; j < 8; ++j) {
                float wv = wdp[i * 8 + j];
#pragma unroll
                for (int p = 0; p < 8; ++p)
                    acc2[p] = fmaf(wv, win[p + 1 + j], acc2[p]);
            }
        }
        us8v o8;
#pragma unroll
        for (int p = 0; p < 8; ++p) o8[p] = (short)f2bf(gc * acc2[p] + bcv);
        *(us8v*)&U[(size_t)bc * 4096 + h * 64 + w0] = o8;
    }
}

// ---------------------------------------------------------------------------
// U (B,512,4096) bf16 -> Ut (B,4096,512) bf16.  64p x 64c LDS tiles.
// ---------------------------------------------------------------------------
__global__ __launch_bounds__(256)
void transpose_cp_kernel(const unsigned short* __restrict__ U, unsigned short* __restrict__ Ut)
{
    int pt = blockIdx.x;               // p-tile 0..63
    int b  = blockIdx.y;
    const unsigned short* Ub = U + (size_t)b * 512 * 4096;
    unsigned short* Utb = Ut + (size_t)b * 4096 * 512;
    __shared__ unsigned short tile[64][72];
    int t = threadIdx.x;
    int p0 = pt * 64;

    for (int cc = 0; cc < 8; ++cc) {
        int c0 = cc * 64;
        __syncthreads();
        {
            int cl = t >> 2, px = (t & 3) * 16;
            const unsigned short* src = &Ub[(size_t)(c0 + cl) * 4096 + p0 + px];
            *(us8v*)&tile[cl][px]     = *(const us8v*)src;
            *(us8v*)&tile[cl][px + 8] = *(const us8v*)(src + 8);
        }
        __syncthreads();
        {
            int pl = t >> 2, cx = (t & 3) * 16;
            us8v o0, o1;
#pragma unroll
            for (int e = 0; e < 8; ++e) {
                o0[e] = tile[cx + e][pl];
                o1[e] = tile[cx + 8 + e][pl];
            }
            unsigned short* dst = &Utb[(size_t)(p0 + pl) * 512 + c0 + cx];
            *(us8v*)dst       = o0;
            *(us8v*)(dst + 8) = o1;
        }
    }
}

// ---------------------------------------------------------------------------
extern "C" void kernel_launch(void* const* d_in, const int* in_sizes, int n_in,
                              void* d_out, int out_size, void* d_ws, size_t ws_size,
                              hipStream_t stream)
{
    (void)in_sizes; (void)n_in; (void)out_size;
    const float* x     = (const float*)d_in[0];
    const float* w_lc1 = (const float*)d_in[1];
    const float* g1    = (const float*)d_in[2];
    const float* b1    = (const float*)d_in[3];
    const float* w_lc2 = (const float*)d_in[4];
    const float* g2    = (const float*)d_in[5];
    const float* b2    = (const float*)d_in[6];
    const float* w_qkv = (const float*)d_in[7];
    const float* rt    = (const float*)d_in[8];
    const float* w_dw  = (const float*)d_in[9];
    const float* g3    = (const float*)d_in[10];
    const float* b3    = (const float*)d_in[11];
    const float* w_pw  = (const float*)d_in[12];
    float* out = (float*)d_out;

    unsigned short* S        = (unsigned short*)d_ws;
    unsigned short* local_us = S;
    unsigned short* xt_us    = S + 16777216;
    unsigned short* attnO    = xt_us;                   // alias: attn out (bf16)
    unsigned short* u_us     = xt_us;                   // alias: U in-place over attnO
    unsigned short* wt3_us   = S + 34619392;
    unsigned short* wq_us    = S + 36978688;
    unsigned short* wpw_us   = S + 37765120;
    float*          bsum     = (float*)(S + 38027264);
    float*          biasM    = (float*)(S + 38028288);
    unsigned short* qkv_us   = S + 38552576;
    unsigned short* ut_us    = local_us;                // alias: Ut after local dead

    const bool full = ws_size >= (size_t)(38552576 + 50331648) * 2;  // 177.77 MB

    repack_kernel<<<dim3(9216), 256, 0, stream>>>(w_lc2, w_lc1, w_qkv, w_pw,
                                                  g1, g2, b1, b2, rt,
                                                  wt3_us, wq_us, wpw_us, bsum, biasM);
    pad_transpose_kernel<<<dim3(66, 8), 256, 0, stream>>>(x, xt_us);
    mfma_gemm256<9, true, unsigned short><<<dim3(16, 2, 8), 512, 0, stream>>>(
        xt_us, wt3_us, bsum, local_us, 512);

    if (full) {
        mfma_gemm256<1, true, unsigned short><<<dim3(16, 6, 8), 512, 0, stream>>>(
            xt_us, wq_us, nullptr, qkv_us, 1536);
        attn_mfma_kernel<<<dim3(256, 8), 256, 0, stream>>>(qkv_us, biasM, attnO);
    } else {
        for (int b = 0; b < 8; ++b) {
            mfma_gemm256<1, true, unsigned short><<<dim3(16, 6, 1), 512, 0, stream>>>(
                xt_us + (size_t)b * 4356 * 512, wq_us, nullptr, qkv_us, 1536);
            attn_mfma_kernel<<<dim3(256, 1), 256, 0, stream>>>(
                qkv_us, biasM, attnO + (size_t)b * 2097152);
        }
    }

    pooldw_kernel<<<dim3(4096), 256, 0, stream>>>(attnO, local_us, w_dw, g3, b3, u_us);
    transpose_cp_kernel<<<dim3(64, 8), 256, 0, stream>>>(u_us, ut_us);
    mfma_gemm256<1, false, float><<<dim3(16, 2, 8), 512, 0, stream>>>(
        ut_us, wpw_us, nullptr, out, 512);
}